// Round 4
// baseline (48406.699 us; speedup 1.0000x reference)
//
#include <hip/hip_runtime.h>
#include <math.h>

#define FH 384
#define KF 193

static __device__ __forceinline__ float softt(float v, float b) {
    return copysignf(fmaxf(fabsf(v) - b, 0.f), v);
}

// ---------------- twiddle tables ----------------
__global__ void init_tf_k(float2* Tf) {
    int idx = blockIdx.x * 256 + threadIdx.x;
    if (idx >= FH * KF) return;
    int w = idx / KF, k = idx % KF;
    int m = (w * k) % FH;
    float th = (float)(6.283185307179586 / FH) * (float)m;
    float2 v; v.x = cosf(th); v.y = -sinf(th);
    Tf[idx] = v;
}
__global__ void init_ef_k(float2* Ef, int inv) {
    int idx = blockIdx.x * 256 + threadIdx.x;
    if (idx >= FH * FH) return;
    int h = idx / FH, j = idx % FH;
    int m = (h * j) % FH;
    float th = (float)(6.283185307179586 / FH) * (float)m;
    float2 v;
    if (inv) { v.x = cosf(th) * (1.f/FH); v.y =  sinf(th) * (1.f/FH); }
    else     { v.x = cosf(th);            v.y = -sinf(th); }
    Ef[idx] = v;
}
__global__ void init_ui_k(float2* Ui) {
    int idx = blockIdx.x * 256 + threadIdx.x;
    if (idx >= KF * FH) return;
    int k = idx / FH, x = idx % FH;
    int m = (k * x) % FH;
    float th = (float)(6.283185307179586 / FH) * (float)m;
    float ck = (k == 0 || k == FH/2) ? (1.f/FH) : (2.f/FH);
    float2 v; v.x = ck * cosf(th); v.y = -ck * sinf(th);
    Ui[idx] = v;
}

// ---------------- w0 centering ----------------
__global__ void w0c_kernel(const float* __restrict__ w0, float* __restrict__ w0c) {
    int t = threadIdx.x;
    if (t < 48) {
        float m = 0.f;
        for (int d = 0; d < 9; ++d) m += w0[t*9+d];
        m *= (1.f/9.f);
        for (int d = 0; d < 9; ++d) w0c[t*9+d] = w0[t*9+d] - m;
    }
}

// ---------------- 3x3 conv (XLA cross-correlation, SAME), blockIdx.z = image ----------------
__global__ __launch_bounds__(256) void conv3x3_kernel(
    const float* __restrict__ inp0, const float* __restrict__ w,
    float* __restrict__ outp0, int Cin, int flip,
    size_t inImgStride, size_t outImgStride)
{
    const float* inp  = inp0  + (size_t)blockIdx.z * inImgStride;
    float*       outp = outp0 + (size_t)blockIdx.z * outImgStride;
    __shared__ float tile[18][19];
    __shared__ float wl[16*16*9];
    int x0 = blockIdx.x * 16, y0 = blockIdx.y * 16;
    int t = threadIdx.x;
    int tx = t & 15, ty = t >> 4;
    int nw = 16 * Cin * 9;
    for (int i = t; i < nw; i += 256) {
        int d = i % 9;
        wl[i] = flip ? w[i + 8 - 2*d] : w[i];
    }
    float acc[16];
#pragma unroll
    for (int co = 0; co < 16; ++co) acc[co] = 0.f;
    for (int ci = 0; ci < Cin; ++ci) {
        __syncthreads();
        for (int i = t; i < 18*18; i += 256) {
            int yy = i / 18, xx = i % 18;
            int gy = y0 - 1 + yy, gx = x0 - 1 + xx;
            float v = 0.f;
            if (gy >= 0 && gy < 256 && gx >= 0 && gx < 256)
                v = inp[((size_t)ci*256 + gy)*256 + gx];
            tile[yy][xx] = v;
        }
        __syncthreads();
        float v[9];
#pragma unroll
        for (int dy = 0; dy < 3; dy++)
#pragma unroll
            for (int dx = 0; dx < 3; dx++) v[dy*3+dx] = tile[ty+dy][tx+dx];
#pragma unroll
        for (int co = 0; co < 16; co++) {
            const float* wp = &wl[(co*Cin+ci)*9];
            acc[co] += v[0]*wp[0]+v[1]*wp[1]+v[2]*wp[2]
                     + v[3]*wp[3]+v[4]*wp[4]+v[5]*wp[5]
                     + v[6]*wp[6]+v[7]*wp[7]+v[8]*wp[8];
        }
    }
#pragma unroll
    for (int co = 0; co < 16; co++)
        outp[((size_t)co*256 + (y0+ty))*256 + (x0+tx)] = acc[co];
}

// ---------------- z init: circshift(22,22) of padded fy9 + soft threshold (G images) ------
__global__ void zinit_kernel(const float* __restrict__ fy9, const float* __restrict__ b0,
                             float* __restrict__ z, int total)
{
    int idx = blockIdx.x*256 + threadIdx.x;
    if (idx >= total) return;
    int x = idx % FH; int r = idx / FH; int y = r % FH; int plane = r / FH;
    int c = plane & 15;
    int Y = y + 22; if (Y >= FH) Y -= FH;
    int X = x + 22; if (X >= FH) X -= FH;
    int yy = Y - 44, xx = X - 44;
    float v = 0.f;
    if (yy >= 0 && yy < 256 && xx >= 0 && xx < 256)
        v = fy9[((size_t)plane*256 + yy)*256 + xx];
    z[idx] = softt(v, b0[c]);
}

// ---------------- row pass R2C: 128x64 tile, 8x4 micro ----------------
// out[(y*B+plane)*KF+k] = sum_w softt(win(plane,y,w)) * Tf[w][k]
__global__ __launch_bounds__(256) void r2c_row(
    const float* __restrict__ inp, int inH, int inW, int offY, int offX,
    const float* __restrict__ thr,
    const float2* __restrict__ Tf, float2* __restrict__ outp, int B)
{
    __shared__ float  As[16][132];   // 132 floats = 528 B row stride (16B-aligned)
    __shared__ float2 Bs[16][66];
    int row0 = blockIdx.y * 128, col0 = blockIdx.x * 64;
    int tid = threadIdx.x, tx = tid & 15, ty = tid >> 4;
    int plane = row0 / FH;
    int y0 = row0 - plane * FH;
    float ar[8][4], ai[8][4];
#pragma unroll
    for (int i = 0; i < 8; i++)
#pragma unroll
        for (int j = 0; j < 4; j++) { ar[i][j] = 0.f; ai[i][j] = 0.f; }
    bool nz = (y0 + 128 > offY) && (y0 < offY + inH);
    if (nz) {
        float bthr = thr ? thr[plane & 15] : 0.f;
        int ktlo = (offX >> 4) << 4;
        int kthi = offX + inW;
        for (int kt = ktlo; kt < kthi; kt += 16) {
#pragma unroll
            for (int l = 0; l < 8; l++) {
                int i = tid + l*256;
                int m = i >> 4, kk = i & 15;
                int y = y0 + m, wq = kt + kk;
                int yy = y - offY, xx = wq - offX;
                float v = 0.f;
                if (yy >= 0 && yy < inH && xx >= 0 && xx < inW)
                    v = inp[((size_t)plane*inH + yy)*inW + xx];
                if (thr) v = softt(v, bthr);
                As[kk][m] = v;
            }
#pragma unroll
            for (int l = 0; l < 4; l++) {
                int i = tid + l*256;
                int kk = i >> 6, nn = i & 63;
                int gn = col0 + nn;
                float2 v; v.x = 0.f; v.y = 0.f;
                if (gn < KF) v = Tf[(kt+kk)*KF + gn];
                Bs[kk][nn] = v;
            }
            __syncthreads();
#pragma unroll
            for (int kk = 0; kk < 16; kk++) {
                float a[8]; float2 b[4];
#pragma unroll
                for (int i = 0; i < 8; i++) a[i] = As[kk][ty*8+i];
#pragma unroll
                for (int j = 0; j < 4; j++) b[j] = Bs[kk][tx + 16*j];
#pragma unroll
                for (int i = 0; i < 8; i++)
#pragma unroll
                    for (int j = 0; j < 4; j++) {
                        ar[i][j] += a[i]*b[j].x;
                        ai[i][j] += a[i]*b[j].y;
                    }
            }
            __syncthreads();
        }
    }
#pragma unroll
    for (int i = 0; i < 8; i++) {
        int y = y0 + ty*8 + i;
#pragma unroll
        for (int j = 0; j < 4; j++) {
            int gn = col0 + tx + 16*j;
            if (gn < KF) {
                float2 tv; tv.x = ar[i][j]; tv.y = ai[i][j];
                outp[((size_t)y*B + plane)*KF + gn] = tv;
            }
        }
    }
}

// ---------------- col pass C2C: 128x64 tile, 8x4 micro ----------------
__global__ __launch_bounds__(256) void zgemm_col(
    const float2* __restrict__ E, const float2* __restrict__ Bm,
    float2* __restrict__ Cm, int N)
{
    __shared__ float2 As[16][130];   // 130 float2 = 1040 B row stride (16B-aligned)
    __shared__ float2 Bs[16][66];
    int row0 = blockIdx.y * 128, col0 = blockIdx.x * 64;
    int tid = threadIdx.x, tx = tid & 15, ty = tid >> 4;
    float ar[8][4], ai[8][4];
#pragma unroll
    for (int i = 0; i < 8; i++)
#pragma unroll
        for (int j = 0; j < 4; j++) { ar[i][j] = 0.f; ai[i][j] = 0.f; }
    for (int kt = 0; kt < FH; kt += 16) {
#pragma unroll
        for (int l = 0; l < 8; l++) {
            int i = tid + l*256;
            int m = i >> 4, kk = i & 15;
            As[kk][m] = E[(size_t)(row0+m)*FH + kt + kk];
        }
#pragma unroll
        for (int l = 0; l < 4; l++) {
            int i = tid + l*256;
            int kk = i >> 6, nn = i & 63;
            int gn = col0 + nn;
            float2 v; v.x = 0.f; v.y = 0.f;
            if (gn < N) v = Bm[(size_t)(kt+kk)*N + gn];
            Bs[kk][nn] = v;
        }
        __syncthreads();
#pragma unroll
        for (int kk = 0; kk < 16; kk++) {
            float2 a[8], b[4];
#pragma unroll
            for (int i = 0; i < 8; i++) a[i] = As[kk][ty*8+i];
#pragma unroll
            for (int j = 0; j < 4; j++) b[j] = Bs[kk][tx + 16*j];
#pragma unroll
            for (int i = 0; i < 8; i++)
#pragma unroll
                for (int j = 0; j < 4; j++) {
                    ar[i][j] += a[i].x*b[j].x - a[i].y*b[j].y;
                    ai[i][j] += a[i].x*b[j].y + a[i].y*b[j].x;
                }
        }
        __syncthreads();
    }
#pragma unroll
    for (int i = 0; i < 8; i++) {
        int gm = row0 + ty*8 + i;
#pragma unroll
        for (int j = 0; j < 4; j++) {
            int gn = col0 + tx + 16*j;
            if (gn < N) {
                float2 tv; tv.x = ar[i][j]; tv.y = ai[i][j];
                Cm[(size_t)gm*N + gn] = tv;
            }
        }
    }
}

// ---------------- row pass C2R: 128x64 tile, 8x4 micro ----------------
// out[plane][y][x] = sum_k A[(y*B+plane)*193+k].Ui[k][x]
__global__ __launch_bounds__(256) void c2r_row(
    const float2* __restrict__ Ain, const float2* __restrict__ Ui,
    float* __restrict__ outp, int B)
{
    __shared__ float2 As[16][130];
    __shared__ float2 Bs[16][66];
    int row0 = blockIdx.y * 128, col0 = blockIdx.x * 64;
    int tid = threadIdx.x, tx = tid & 15, ty = tid >> 4;
    float acc[8][4];
#pragma unroll
    for (int i = 0; i < 8; i++)
#pragma unroll
        for (int j = 0; j < 4; j++) acc[i][j] = 0.f;
    for (int kt = 0; kt < KF; kt += 16) {
#pragma unroll
        for (int l = 0; l < 8; l++) {
            int i = tid + l*256;
            int m = i >> 4, kk = i & 15;
            int gk = kt + kk;
            float2 v; v.x = 0.f; v.y = 0.f;
            if (gk < KF) v = Ain[(size_t)(row0+m)*KF + gk];
            As[kk][m] = v;
        }
#pragma unroll
        for (int l = 0; l < 4; l++) {
            int i = tid + l*256;
            int kk = i >> 6, nn = i & 63;
            int gk = kt + kk;
            float2 v; v.x = 0.f; v.y = 0.f;
            if (gk < KF) v = Ui[(size_t)gk*FH + col0 + nn];
            Bs[kk][nn] = v;
        }
        __syncthreads();
#pragma unroll
        for (int kk = 0; kk < 16; kk++) {
            float2 a[8], b[4];
#pragma unroll
            for (int i = 0; i < 8; i++) a[i] = As[kk][ty*8+i];
#pragma unroll
            for (int j = 0; j < 4; j++) b[j] = Bs[kk][tx + 16*j];
#pragma unroll
            for (int i = 0; i < 8; i++)
#pragma unroll
                for (int j = 0; j < 4; j++)
                    acc[i][j] += a[i].x*b[j].x + a[i].y*b[j].y;
        }
        __syncthreads();
    }
#pragma unroll
    for (int i = 0; i < 8; i++) {
        int gm = row0 + ty*8 + i;
        int y = gm / B, bi = gm - y*B;
#pragma unroll
        for (int j = 0; j < 4; j++)
            outp[((size_t)bi*FH + y)*FH + col0 + tx + 16*j] = acc[i][j];
    }
}

// ---------------- elementwise frequency-domain updates (G images) ----------------
// spectra layout: [h][plane][k], plane = img*16 + c; Fk layout [h][img][k]
__global__ void fg_kernel(const float2* __restrict__ Ffy, const float2* __restrict__ Fz,
                          const float2* __restrict__ Fk, const float* __restrict__ zetas,
                          int L, int total, float2* __restrict__ Fg)
{
    int idx = blockIdx.x*256 + threadIdx.x;
    if (idx >= total) return;
    int k = idx % KF; int r = idx / KF;
    int c = r & 15; int hi = r >> 4;     // hi = h*G + img
    float zeta = 10.f * zetas[L*16 + c];
    float2 fk = Fk[(size_t)hi*KF + k];
    float2 fy = Ffy[idx];
    float2 fz = Fz[idx];
    float nx = zeta*(fk.x*fy.x + fk.y*fy.y) + fz.x;
    float ny = zeta*(fk.x*fy.y - fk.y*fy.x) + fz.y;
    float den = zeta*(fk.x*fk.x + fk.y*fk.y) + 1.f + 1e-8f;
    float inv = 1.f/den;
    float2 o; o.x = nx*inv; o.y = ny*inv;
    Fg[idx] = o;
}

__global__ void knum_kernel(const float2* __restrict__ Fz, const float2* __restrict__ Ffy,
                            const float2* __restrict__ Fk, const float* __restrict__ kprox,
                            int L, int total, float2* __restrict__ outk)
{
    int idx = blockIdx.x*256 + threadIdx.x;
    if (idx >= total) return;
    int k = idx % KF; int r = idx / KF;  // r = h*G + img
    float zk = kprox[L];
    float s1x = 0.f, s1y = 0.f, s2 = 0.f;
    for (int c = 0; c < 16; ++c) {
        size_t bi = ((size_t)r*16 + c)*KF + k;
        float2 fz = Fz[bi], fy = Ffy[bi];
        s1x += fz.x*fy.x + fz.y*fy.y;
        s1y += fz.x*fy.y - fz.y*fy.x;
        s2  += fz.x*fz.x + fz.y*fz.y;
    }
    float2 fk = Fk[idx];
    float nx = zk*s1x + fk.x, ny = zk*s1y + fk.y;
    float den = zk*s2 + 1.f + 1e-8f;
    float inv = 1.f/den;
    float2 o; o.x = nx*inv; o.y = ny*inv;
    outk[idx] = o;
}

// ---------------- kernel (blur-kernel) update, blockIdx.y/x = image ----------------
__device__ __forceinline__ void lse_comb(float& m, float& s, float m2, float s2)
{
    if (m2 > m) { s = s * expf(m - m2) + s2; m = m2; }
    else        { s = s + s2 * expf(m2 - m); }
}

__global__ __launch_bounds__(256) void lse_part_kernel(const float* __restrict__ kraw0,
                                                       float2* __restrict__ parts)
{
    int img = blockIdx.y;
    const float* kraw = kraw0 + (size_t)img*FH*FH;
    int b = blockIdx.x, t = threadIdx.x;
    float m = -1e30f, s = 0.f;
    for (int i = b*256 + t; i < FH*FH; i += 64*256) {
        float v = 100.f * kraw[i];
        lse_comb(m, s, v, 1.f);
    }
    __shared__ float sm[256], ss[256];
    sm[t] = m; ss[t] = s;
    __syncthreads();
    for (int st = 128; st > 0; st >>= 1) {
        if (t < st) {
            float mm = sm[t], sc = ss[t];
            lse_comb(mm, sc, sm[t+st], ss[t+st]);
            sm[t] = mm; ss[t] = sc;
        }
        __syncthreads();
    }
    if (t == 0) { float2 o; o.x = sm[0]; o.y = ss[0]; parts[img*64 + b] = o; }
}

__global__ void lse_final_kernel(const float2* __restrict__ parts, float* __restrict__ kmaxB)
{
    int img = blockIdx.x;
    int t = threadIdx.x;
    __shared__ float sm[64], ss[64];
    float2 p = parts[img*64 + t];
    sm[t] = p.x; ss[t] = p.y;
    __syncthreads();
    for (int st = 32; st > 0; st >>= 1) {
        if (t < st) {
            float mm = sm[t], sc = ss[t];
            lse_comb(mm, sc, sm[t+st], ss[t+st]);
            sm[t] = mm; ss[t] = sc;
        }
        __syncthreads();
    }
    if (t == 0) kmaxB[img] = (sm[0] + logf(ss[0])) * 0.01f;
}

__global__ void zero_kernel(float* __restrict__ p, int n)
{
    int i = blockIdx.x*256 + threadIdx.x;
    if (i < n) p[i] = 0.f;
}

__global__ void kdelta_kernel(float* __restrict__ kful, int G)
{
    int t = threadIdx.x;
    if (t < G) kful[(size_t)t*FH*FH + 22*FH + 22] = 1.f;
}

__global__ __launch_bounds__(256) void knew_kernel(const float* __restrict__ kraw0,
    const float* __restrict__ kmax, const float* __restrict__ kb, int L,
    float* __restrict__ kful0)
{
    int img = blockIdx.x;
    const float* kraw = kraw0 + (size_t)img*FH*FH;
    float*       kful = kful0 + (size_t)img*FH*FH;
    int t = threadIdx.x;
    float thr = 0.01f * kb[L] * kmax[img];
    float vs[8]; float loc = 0.f;
#pragma unroll
    for (int ii = 0; ii < 8; ++ii) {
        int i = t + ii*256;
        float v = 0.f;
        if (i < 45*45) {
            int y = i/45, x = i - y*45;
            v = fmaxf(kraw[y*FH + x] - thr, 0.f);
        }
        vs[ii] = v; loc += v;
    }
    __shared__ float sr[256];
    sr[t] = loc; __syncthreads();
    for (int st = 128; st > 0; st >>= 1) { if (t < st) sr[t] += sr[t+st]; __syncthreads(); }
    float den = sr[0] + 1e-8f;
#pragma unroll
    for (int ii = 0; ii < 8; ++ii) {
        int i = t + ii*256;
        if (i < 45*45) {
            int y = i/45, x = i - y*45;
            float v = vs[ii] + ((y == 22 && x == 22) ? 1e-8f : 0.f);
            kful[y*FH + x] = v / den;
        }
    }
}

// ---------------- Fw0 (direct 9-term DFT of shifted 3x3), image-independent ----------------
__global__ void fw0_kernel(const float* __restrict__ w0c, const float2* __restrict__ Ef,
                           float2* __restrict__ Fw0)
{
    int idx = blockIdx.x*256 + threadIdx.x;
    if (idx >= 48*FH*KF) return;
    int k = idx % KF; int r = idx / KF;
    int c = r & 15; int r2 = r >> 4;
    int ci = r2 % 3; int h = r2 / 3;
    float accx = 0.f, accy = 0.f;
#pragma unroll
    for (int ky = 0; ky < 3; ++ky) {
        int a1 = ky - 1; if (a1 < 0) a1 += FH;
        float2 e1 = Ef[h*FH + a1];
#pragma unroll
        for (int kx = 0; kx < 3; ++kx) {
            int a2 = kx - 1; if (a2 < 0) a2 += FH;
            float2 e2 = Ef[k*FH + a2];
            float wv = w0c[((c*3 + ci)*3 + ky)*3 + kx];
            float tr = e1.x*e2.x - e1.y*e2.y;
            float ti = e1.x*e2.y + e1.y*e2.x;
            accx += wv*tr; accy += wv*ti;
        }
    }
    float2 o; o.x = accx; o.y = accy;
    Fw0[idx] = o;
}

// ---------------- final per-bin 3x3 Hermitian Wiener solve (G images) ----------------
// Fk [h][img][k]; Fy/Fx [h][img*3+ch][k]; Fg2 [h][img*16+c][k]; Fw0 [h][48][k]
__global__ void wiener_kernel(const float2* __restrict__ Fk, const float2* __restrict__ Fy,
    const float2* __restrict__ Fw0, const float2* __restrict__ Fg2,
    const float* __restrict__ eta, int G, int total, float2* __restrict__ Fx)
{
    int idx = blockIdx.x*256 + threadIdx.x;
    if (idx >= total) return;
    int k = idx % KF; int r = idx / KF;   // r = h*G + img
    int h = r / G;
    float2 fk = Fk[idx];
    float fksq = fk.x*fk.x + fk.y*fk.y;
    float2 fyr = Fy[((size_t)3*r + 0)*KF + k];
    float2 fyg = Fy[((size_t)3*r + 1)*KF + k];
    float2 fyb = Fy[((size_t)3*r + 2)*KF + k];
    float Crr = fksq, Cgg = fksq, Cbb = fksq;
    float2 Crg, Crb, Cgb;
    Crg.x = Crg.y = Crb.x = Crb.y = Cgb.x = Cgb.y = 0.f;
    float2 Br, Bg, Bb;
    Br.x = fk.x*fyr.x + fk.y*fyr.y; Br.y = fk.x*fyr.y - fk.y*fyr.x;
    Bg.x = fk.x*fyg.x + fk.y*fyg.y; Bg.y = fk.x*fyg.y - fk.y*fyg.x;
    Bb.x = fk.x*fyb.x + fk.y*fyb.y; Bb.y = fk.x*fyb.y - fk.y*fyb.x;
    for (int c = 0; c < 16; ++c) {
        float es = 10.f * eta[c];
        float2 wr = Fw0[((size_t)h*48 +  0 + c)*KF + k];
        float2 wg = Fw0[((size_t)h*48 + 16 + c)*KF + k];
        float2 wb = Fw0[((size_t)h*48 + 32 + c)*KF + k];
        float2 g  = Fg2[((size_t)r*16 + c)*KF + k];
        Crr += es*(wr.x*wr.x + wr.y*wr.y);
        Cgg += es*(wg.x*wg.x + wg.y*wg.y);
        Cbb += es*(wb.x*wb.x + wb.y*wb.y);
        Crg.x += es*(wr.x*wg.x + wr.y*wg.y); Crg.y += es*(wr.x*wg.y - wr.y*wg.x);
        Crb.x += es*(wr.x*wb.x + wr.y*wb.y); Crb.y += es*(wr.x*wb.y - wr.y*wb.x);
        Cgb.x += es*(wg.x*wb.x + wg.y*wb.y); Cgb.y += es*(wg.x*wb.y - wg.y*wb.x);
        Br.x += es*(wr.x*g.x + wr.y*g.y); Br.y += es*(wr.x*g.y - wr.y*g.x);
        Bg.x += es*(wg.x*g.x + wg.y*g.y); Bg.y += es*(wg.x*g.y - wg.y*g.x);
        Bb.x += es*(wb.x*g.x + wb.y*g.y); Bb.y += es*(wb.x*g.y - wb.y*g.x);
    }
    float Crg_sq = Crg.x*Crg.x + Crg.y*Crg.y;
    float Crb_sq = Crb.x*Crb.x + Crb.y*Crb.y;
    float Cgb_sq = Cgb.x*Cgb.x + Cgb.y*Cgb.y;
    float Irr = Cgg*Cbb - Cgb_sq;
    float Igg = Crr*Cbb - Crb_sq;
    float Ibb = Crr*Cgg - Crg_sq;
    float2 Irg, Irb, Igb;
    Irg.x = (Cgb.x*Crb.x + Cgb.y*Crb.y) - Cbb*Crg.x;
    Irg.y = (Cgb.x*Crb.y - Cgb.y*Crb.x) - Cbb*Crg.y;
    Irb.x = (Crg.x*Cgb.x - Crg.y*Cgb.y) - Cgg*Crb.x;
    Irb.y = (Crg.x*Cgb.y + Crg.y*Cgb.x) - Cgg*Crb.y;
    Igb.x = (Crg.x*Crb.x + Crg.y*Crb.y) - Crr*Cgb.x;
    Igb.y = (Crg.x*Crb.y - Crg.y*Crb.x) - Crr*Cgb.y;
    float tx_ = Crg.x*Cgb.x - Crg.y*Cgb.y;
    float ty_ = Crg.x*Cgb.y + Crg.y*Cgb.x;
    float den = Crr*Irr - Cgg*Crb_sq - Cbb*Crg_sq + 2.f*(tx_*Crb.x + ty_*Crb.y) + 1e-8f;
    float inv = 1.f/den;
    float2 o;
    o.x = (Irr*Br.x + (Irg.x*Bg.x - Irg.y*Bg.y) + (Irb.x*Bb.x - Irb.y*Bb.y))*inv;
    o.y = (Irr*Br.y + (Irg.x*Bg.y + Irg.y*Bg.x) + (Irb.x*Bb.y + Irb.y*Bb.x))*inv;
    Fx[((size_t)3*r + 0)*KF + k] = o;
    o.x = ((Irg.x*Br.x + Irg.y*Br.y) + Igg*Bg.x + (Igb.x*Bb.x - Igb.y*Bb.y))*inv;
    o.y = ((Irg.x*Br.y - Irg.y*Br.x) + Igg*Bg.y + (Igb.x*Bb.y + Igb.y*Bb.x))*inv;
    Fx[((size_t)3*r + 1)*KF + k] = o;
    o.x = ((Irb.x*Br.x + Irb.y*Br.y) + (Igb.x*Bg.x + Igb.y*Bg.y) + Ibb*Bb.x)*inv;
    o.y = ((Irb.x*Br.y - Irb.y*Br.x) + (Igb.x*Bg.y - Igb.y*Bg.x) + Ibb*Bb.y)*inv;
    Fx[((size_t)3*r + 2)*KF + k] = o;
}

// ---------------- output assembly (G images) ----------------
__global__ void crop_kernel(const float* __restrict__ sp, float* __restrict__ outp, int total)
{
    int idx = blockIdx.x*256 + threadIdx.x;
    if (idx >= total) return;
    int x = idx & 255; int r = idx >> 8; int y = r & 255; int plane = r >> 8;
    outp[idx] = sp[((size_t)plane*FH + (y+22))*FH + (x+22)];
}

__global__ void kcopy_kernel(const float* __restrict__ kful, float* __restrict__ outp, int total)
{
    int idx = blockIdx.x*256 + threadIdx.x;
    if (idx >= total) return;
    int rem = idx % 2025; int img = idx / 2025;
    int x = rem % 45; int y = rem / 45;
    outp[idx] = kful[(size_t)img*FH*FH + y*FH + x];
}

// =====================================================================
extern "C" void kernel_launch(void* const* d_in, const int* in_sizes, int n_in,
                              void* d_out, int out_size, void* d_ws, size_t ws_size,
                              hipStream_t stream)
{
    (void)in_sizes; (void)n_in; (void)out_size;
    const float* blurred = (const float*)d_in[0];
    const float* w0      = (const float*)d_in[1];
    const float* wsw     = (const float*)d_in[2];
    const float* biases  = (const float*)d_in[3];
    const float* kbias   = (const float*)d_in[4];
    const float* kprox   = (const float*)d_in[5];
    const float* zetas   = (const float*)d_in[6];
    const float* eta     = (const float*)d_in[7];
    float* outp = (float*)d_out;

    auto al = [](size_t b) { return (b + 255) & ~(size_t)255; };
    auto need = [&](int G) -> size_t {
        size_t s = 0;
        s += al((size_t)FH*KF*8);                 // Tf
        s += 2*al((size_t)FH*FH*8);               // Ef, Ei
        s += al((size_t)KF*FH*8);                 // Ui
        s += al(432*4);                           // w0c
        s += al((size_t)10*G*16*65536*4);         // fyN
        s += al((size_t)G*16*FH*FH*4);            // zsp
        s += 3*al((size_t)G*16*FH*KF*8);          // mid, FzFg, Ffy
        s += 3*al((size_t)G*FH*KF*8);             // Fk, kfA, kfB
        s += 2*al((size_t)G*FH*FH*4);             // kraw, kful
        s += 2*al((size_t)G*3*FH*KF*8);           // FyB, FxB
        s += al((size_t)G*64*8) + al(256);        // lseP, kmax
        return s;
    };
    int G = 4;
    while (G > 1 && need(G) > ws_size) G >>= 1;

    char* base = (char*)d_ws;
    size_t off = 0;
    auto alloc = [&](size_t bytes) -> void* {
        void* p = (void*)(base + off);
        off += (bytes + 255) & ~(size_t)255;
        return p;
    };
    float2* Tf   = (float2*)alloc((size_t)FH*KF*8);
    float2* Ef   = (float2*)alloc((size_t)FH*FH*8);
    float2* Ei   = (float2*)alloc((size_t)FH*FH*8);
    float2* Ui   = (float2*)alloc((size_t)KF*FH*8);
    float*  w0cB = (float*)alloc(432*4);
    float*  fyN  = (float*)alloc((size_t)10*G*16*65536*4);
    float*  zsp  = (float*)alloc((size_t)G*16*FH*FH*4);
    float2* mid  = (float2*)alloc((size_t)G*16*FH*KF*8);
    float2* FzFg = (float2*)alloc((size_t)G*16*FH*KF*8);
    float2* Ffy  = (float2*)alloc((size_t)G*16*FH*KF*8);
    float2* Fk   = (float2*)alloc((size_t)G*FH*KF*8);
    float2* kfA  = (float2*)alloc((size_t)G*FH*KF*8);
    float2* kfB  = (float2*)alloc((size_t)G*FH*KF*8);
    float*  kraw = (float*)alloc((size_t)G*FH*FH*4);
    float*  kful = (float*)alloc((size_t)G*FH*FH*4);
    float2* FyB  = (float2*)alloc((size_t)G*3*FH*KF*8);
    float2* FxB  = (float2*)alloc((size_t)G*3*FH*KF*8);
    float2* lseP = (float2*)alloc((size_t)G*64*8);
    float*  kmaxB= (float*)alloc(256);
    // Fw0 (28.45 MB) overlays fyN (>= 41.9 MB even at G=1) — dead by final stage
    float2* Fw0B = (float2*)fyN;

    // tables + weight prep (image-independent)
    init_tf_k<<<(FH*KF+255)/256, 256, 0, stream>>>(Tf);
    init_ef_k<<<(FH*FH+255)/256, 256, 0, stream>>>(Ef, 0);
    init_ef_k<<<(FH*FH+255)/256, 256, 0, stream>>>(Ei, 1);
    init_ui_k<<<(KF*FH+255)/256, 256, 0, stream>>>(Ui);
    w0c_kernel<<<1, 64, 0, stream>>>(w0, w0cB);

    auto zg = [&](const float2* E_, const float2* Bm, float2* Cm, int Ncols) {
        zgemm_col<<<dim3((Ncols+63)/64, FH/128), 256, 0, stream>>>(E_, Bm, Cm, Ncols);
    };
    auto r2c = [&](const float* inp, int inH, int inW, int oY, int oX,
                   const float* thr, float2* o, int B) {
        r2c_row<<<dim3((KF+63)/64, B*FH/128), 256, 0, stream>>>(inp, inH, inW, oY, oX, thr, Tf, o, B);
    };
    auto c2r = [&](const float2* Ain, float* o, int B) {
        c2r_row<<<dim3(FH/64, B*FH/128), 256, 0, stream>>>(Ain, Ui, o, B);
    };

    const size_t IMG16 = (size_t)16*65536;        // one layer, one image
    const size_t LAY   = (size_t)G*IMG16;         // one layer, group

    for (int g0 = 0; g0 < 4; g0 += G) {
        const float* img = blurred + (size_t)g0*3*65536;

        // forward conv chain (10 checkpoints, layout [l][img*16+c][y][x])
        conv3x3_kernel<<<dim3(16,16,G), 256, 0, stream>>>(
            img, w0cB, fyN, 3, 1, (size_t)3*65536, IMG16);
        for (int l = 1; l < 10; ++l)
            conv3x3_kernel<<<dim3(16,16,G), 256, 0, stream>>>(
                fyN + (size_t)(l-1)*LAY, wsw + (size_t)(l-1)*2304,
                fyN + (size_t)l*LAY, 16, 0, IMG16, IMG16);

        // z init (circshift + threshold b0), Fz
        int totZ = G*16*FH*FH;
        zinit_kernel<<<(totZ+255)/256, 256, 0, stream>>>(fyN + 9*LAY, biases, zsp, totZ);
        r2c(zsp, FH, FH, 0, 0, nullptr, mid, G*16);
        zg(Ef, mid, FzFg, G*16*KF);

        // k init = delta
        zero_kernel<<<(G*FH*FH+255)/256, 256, 0, stream>>>(kful, G*FH*FH);
        kdelta_kernel<<<1, 64, 0, stream>>>(kful, G);

        int totS = G*16*FH*KF;   // full spectra element count
        int totK = G*FH*KF;      // kernel spectra element count
        for (int it = 0; it < 10; ++it) {
            int Lfy = 9 - it;
            r2c(fyN + (size_t)Lfy*LAY, 256, 256, 44, 44, nullptr, mid, G*16);
            zg(Ef, mid, Ffy, G*16*KF);
            r2c(kful, FH, FH, 0, 0, nullptr, mid, G);
            zg(Ef, mid, Fk, G*KF);
            fg_kernel<<<(totS+255)/256, 256, 0, stream>>>(Ffy, FzFg, Fk, zetas, it, totS, FzFg);
            zg(Ei, FzFg, mid, G*16*KF);
            c2r(mid, zsp, G*16);                    // zsp = irfft(Fg) PRE-threshold
            r2c(zsp, FH, FH, 0, 0, biases + (it+1)*16, mid, G*16);  // fused soft-threshold
            zg(Ef, mid, FzFg, G*16*KF);             // Fz_new
            knum_kernel<<<(totK+255)/256, 256, 0, stream>>>(FzFg, Ffy, Fk, kprox, it, totK, kfA);
            zg(Ei, kfA, kfB, G*KF);
            c2r(kfB, kraw, G);
            lse_part_kernel<<<dim3(64,G), 256, 0, stream>>>(kraw, lseP);
            lse_final_kernel<<<G, 64, 0, stream>>>(lseP, kmaxB);
            knew_kernel<<<G, 256, 0, stream>>>(kraw, kmaxB, kbias, it, kful);
        }

        // ---- final stage for this group ----
        r2c(img, 256, 256, 44, 44, nullptr, mid, 3*G);
        zg(Ef, mid, FyB, 3*G*KF);
        r2c(kful, FH, FH, 0, 0, nullptr, mid, G);
        zg(Ef, mid, Fk, G*KF);
        // Fg2 = rfft(softt(zsp, b_final)) — zsp holds it=9's pre-threshold irfft(Fg)
        r2c(zsp, FH, FH, 0, 0, biases + 11*16, mid, G*16);
        zg(Ef, mid, FzFg, G*16*KF);
        fw0_kernel<<<(48*FH*KF+255)/256, 256, 0, stream>>>(w0cB, Ef, Fw0B);  // overlays fyN
        wiener_kernel<<<(totK+255)/256, 256, 0, stream>>>(Fk, FyB, Fw0B, FzFg, eta, G, totK, FxB);
        zg(Ei, FxB, mid, 3*G*KF);
        c2r(mid, zsp, 3*G);
        int totC = G*3*65536;
        crop_kernel<<<(totC+255)/256, 256, 0, stream>>>(zsp, outp + (size_t)g0*3*65536, totC);
        int totKC = G*2025;
        kcopy_kernel<<<(totKC+255)/256, 256, 0, stream>>>(kful, outp + 786432 + g0*2025, totKC);
    }
}

// Round 5
// 16046.127 us; speedup vs baseline: 3.0167x; 3.0167x over previous
//
#include <hip/hip_runtime.h>
#include <math.h>

#define FH 384
#define KF 193
#define KP 768   // stacked real K' = 2*FH

typedef __attribute__((ext_vector_type(8))) short short8;
typedef __attribute__((ext_vector_type(4))) float f32x4;

static __device__ __forceinline__ float softt(float v, float b) {
    return copysignf(fmaxf(fabsf(v) - b, 0.f), v);
}
static __device__ __forceinline__ unsigned short bf16_rn(float v) {
    unsigned u = __float_as_uint(v);
    unsigned r = (u + 0x7FFFu + ((u >> 16) & 1u)) >> 16;
    return (unsigned short)r;
}
static __device__ __forceinline__ float bf16_to_f(unsigned short h) {
    return __uint_as_float(((unsigned)h) << 16);
}

// ---------------- twiddle tables ----------------
__global__ void init_tf_k(float2* Tf) {
    int idx = blockIdx.x * 256 + threadIdx.x;
    if (idx >= FH * KF) return;
    int w = idx / KF, k = idx % KF;
    int m = (w * k) % FH;
    float th = (float)(6.283185307179586 / FH) * (float)m;
    float2 v; v.x = cosf(th); v.y = -sinf(th);
    Tf[idx] = v;
}
__global__ void init_ef_k(float2* Ef) {
    int idx = blockIdx.x * 256 + threadIdx.x;
    if (idx >= FH * FH) return;
    int h = idx / FH, j = idx % FH;
    int m = (h * j) % FH;
    float th = (float)(6.283185307179586 / FH) * (float)m;
    float2 v; v.x = cosf(th); v.y = -sinf(th);
    Ef[idx] = v;
}
__global__ void init_ui_k(float2* Ui) {
    int idx = blockIdx.x * 256 + threadIdx.x;
    if (idx >= KF * FH) return;
    int k = idx / FH, x = idx % FH;
    int m = (k * x) % FH;
    float th = (float)(6.283185307179586 / FH) * (float)m;
    float ck = (k == 0 || k == FH/2) ? (1.f/FH) : (2.f/FH);
    float2 v; v.x = ck * cosf(th); v.y = -ck * sinf(th);
    Ui[idx] = v;
}

// stacked real DFT matrix for MFMA col pass, bf16 hi/lo:
//   row 2m   : [ er, -ei ] interleaved over t   (produces Re)
//   row 2m+1 : [ ei,  er ]                      (produces Im)
__global__ void init_estack(unsigned short* __restrict__ H, unsigned short* __restrict__ L, int inv)
{
    int idx = blockIdx.x * 256 + threadIdx.x;
    if (idx >= KP * KP) return;
    int gm = idx / KP, kp = idx % KP;
    int m = gm >> 1, comp = gm & 1;
    int t = kp >> 1, ri = kp & 1;
    int mm = (m * t) % FH;
    float th = (float)(6.283185307179586 / FH) * (float)mm;
    float c = cosf(th), s = sinf(th);
    float er, ei;
    if (inv) { er = c * (1.f/FH); ei = s * (1.f/FH); }
    else     { er = c;            ei = -s; }
    float v;
    if (comp == 0) v = (ri == 0) ? er : -ei;
    else           v = (ri == 0) ? ei :  er;
    unsigned short h = bf16_rn(v);
    H[idx] = h;
    L[idx] = bf16_rn(v - bf16_to_f(h));
}

// ---------------- w0 centering ----------------
__global__ void w0c_kernel(const float* __restrict__ w0, float* __restrict__ w0c) {
    int t = threadIdx.x;
    if (t < 48) {
        float m = 0.f;
        for (int d = 0; d < 9; ++d) m += w0[t*9+d];
        m *= (1.f/9.f);
        for (int d = 0; d < 9; ++d) w0c[t*9+d] = w0[t*9+d] - m;
    }
}

// ---------------- 3x3 conv (XLA cross-correlation, SAME), blockIdx.z = image ----------------
__global__ __launch_bounds__(256) void conv3x3_kernel(
    const float* __restrict__ inp0, const float* __restrict__ w,
    float* __restrict__ outp0, int Cin, int flip,
    size_t inImgStride, size_t outImgStride)
{
    const float* inp  = inp0  + (size_t)blockIdx.z * inImgStride;
    float*       outp = outp0 + (size_t)blockIdx.z * outImgStride;
    __shared__ float tile[18][19];
    __shared__ float wl[16*16*9];
    int x0 = blockIdx.x * 16, y0 = blockIdx.y * 16;
    int t = threadIdx.x;
    int tx = t & 15, ty = t >> 4;
    int nw = 16 * Cin * 9;
    for (int i = t; i < nw; i += 256) {
        int d = i % 9;
        wl[i] = flip ? w[i + 8 - 2*d] : w[i];
    }
    float acc[16];
#pragma unroll
    for (int co = 0; co < 16; ++co) acc[co] = 0.f;
    for (int ci = 0; ci < Cin; ++ci) {
        __syncthreads();
        for (int i = t; i < 18*18; i += 256) {
            int yy = i / 18, xx = i % 18;
            int gy = y0 - 1 + yy, gx = x0 - 1 + xx;
            float v = 0.f;
            if (gy >= 0 && gy < 256 && gx >= 0 && gx < 256)
                v = inp[((size_t)ci*256 + gy)*256 + gx];
            tile[yy][xx] = v;
        }
        __syncthreads();
        float v[9];
#pragma unroll
        for (int dy = 0; dy < 3; dy++)
#pragma unroll
            for (int dx = 0; dx < 3; dx++) v[dy*3+dx] = tile[ty+dy][tx+dx];
#pragma unroll
        for (int co = 0; co < 16; co++) {
            const float* wp = &wl[(co*Cin+ci)*9];
            acc[co] += v[0]*wp[0]+v[1]*wp[1]+v[2]*wp[2]
                     + v[3]*wp[3]+v[4]*wp[4]+v[5]*wp[5]
                     + v[6]*wp[6]+v[7]*wp[7]+v[8]*wp[8];
        }
    }
#pragma unroll
    for (int co = 0; co < 16; co++)
        outp[((size_t)co*256 + (y0+ty))*256 + (x0+tx)] = acc[co];
}

// ---------------- z init: circshift(22,22) of padded fy9 + soft threshold (G images) ------
__global__ void zinit_kernel(const float* __restrict__ fy9, const float* __restrict__ b0,
                             float* __restrict__ z, int total)
{
    int idx = blockIdx.x*256 + threadIdx.x;
    if (idx >= total) return;
    int x = idx % FH; int r = idx / FH; int y = r % FH; int plane = r / FH;
    int c = plane & 15;
    int Y = y + 22; if (Y >= FH) Y -= FH;
    int X = x + 22; if (X >= FH) X -= FH;
    int yy = Y - 44, xx = X - 44;
    float v = 0.f;
    if (yy >= 0 && yy < 256 && xx >= 0 && xx < 256)
        v = fy9[((size_t)plane*256 + yy)*256 + xx];
    z[idx] = softt(v, b0[c]);
}

// ---------------- row pass R2C (round-3 64x64 tile, 4x4 micro) ----------------
__global__ __launch_bounds__(256) void r2c_row(
    const float* __restrict__ inp, int inH, int inW, int offY, int offX,
    const float* __restrict__ thr,
    const float2* __restrict__ Tf, float2* __restrict__ outp, int B)
{
    __shared__ float  As[16][65];
    __shared__ float2 Bs[16][66];
    int row0 = blockIdx.y * 64, col0 = blockIdx.x * 64;
    int tid = threadIdx.x, tx = tid & 15, ty = tid >> 4;
    int plane = row0 / FH;
    int y0 = row0 - plane * FH;
    float ar[4][4], ai[4][4];
#pragma unroll
    for (int i = 0; i < 4; i++)
#pragma unroll
        for (int j = 0; j < 4; j++) { ar[i][j] = 0.f; ai[i][j] = 0.f; }
    bool nz = (y0 + 64 > offY) && (y0 < offY + inH);
    if (nz) {
        float bthr = thr ? thr[plane & 15] : 0.f;
        int ktlo = (offX >> 4) << 4;
        int kthi = offX + inW;
        for (int kt = ktlo; kt < kthi; kt += 16) {
#pragma unroll
            for (int l = 0; l < 4; l++) {
                int i = tid + l*256;
                int m = i >> 4, kk = i & 15;
                int y = y0 + m, wq = kt + kk;
                int yy = y - offY, xx = wq - offX;
                float v = 0.f;
                if (yy >= 0 && yy < inH && xx >= 0 && xx < inW)
                    v = inp[((size_t)plane*inH + yy)*inW + xx];
                if (thr) v = softt(v, bthr);
                As[kk][m] = v;
            }
#pragma unroll
            for (int l = 0; l < 4; l++) {
                int i = tid + l*256;
                int kk = i >> 6, nn = i & 63;
                int gn = col0 + nn;
                float2 v; v.x = 0.f; v.y = 0.f;
                if (gn < KF) v = Tf[(kt+kk)*KF + gn];
                Bs[kk][nn] = v;
            }
            __syncthreads();
#pragma unroll
            for (int kk = 0; kk < 16; kk++) {
                float a[4]; float2 b[4];
#pragma unroll
                for (int i = 0; i < 4; i++) a[i] = As[kk][ty*4+i];
#pragma unroll
                for (int j = 0; j < 4; j++) b[j] = Bs[kk][tx + 16*j];
#pragma unroll
                for (int i = 0; i < 4; i++)
#pragma unroll
                    for (int j = 0; j < 4; j++) {
                        ar[i][j] += a[i]*b[j].x;
                        ai[i][j] += a[i]*b[j].y;
                    }
            }
            __syncthreads();
        }
    }
#pragma unroll
    for (int i = 0; i < 4; i++) {
        int y = y0 + ty*4 + i;
#pragma unroll
        for (int j = 0; j < 4; j++) {
            int gn = col0 + tx + 16*j;
            if (gn < KF) {
                float2 tv; tv.x = ar[i][j]; tv.y = ai[i][j];
                outp[((size_t)y*B + plane)*KF + gn] = tv;
            }
        }
    }
}

// ---------------- MFMA col pass: C = E·B (complex), stacked-real bf16x3 ----------------
// EH/EL: [768][768] bf16 stacked DFT matrix (hi/lo). Bm: [384][N] float2. Cm: float* view.
__global__ __launch_bounds__(256) void zgemm_col_mfma(
    const unsigned short* __restrict__ EH, const unsigned short* __restrict__ EL,
    const float2* __restrict__ Bm, float* __restrict__ Cm, int N)
{
    __shared__ unsigned short BhS[4*64*8];   // [ntile][lane][j] fragment-order
    __shared__ unsigned short BlS[4*64*8];
    int col0 = blockIdx.x * 64;
    int row0 = blockIdx.y * 128;             // stacked M'-rows
    int tid = threadIdx.x;
    int wave = tid >> 6, lane = tid & 63;
    int lm = lane & 15, lq = lane >> 4;
    f32x4 acc[2][4];
#pragma unroll
    for (int mi = 0; mi < 2; ++mi)
#pragma unroll
        for (int nj = 0; nj < 4; ++nj) acc[mi][nj] = (f32x4){0.f,0.f,0.f,0.f};
    int arow0 = row0 + wave*32 + lm;        // A-operand row (m = lane&15)
    for (int kt = 0; kt < KP; kt += 32) {
        int tbase = kt >> 1;
        // ---- stage B chunk: 16 complex k-rows x 64 cols, hi/lo split, frag order ----
#pragma unroll
        for (int s = 0; s < 2; ++s) {
            int slot = tid + s*256;
            int pair = slot >> 6;            // 0..7 (t-pair)
            int n    = slot & 63;
            int gn   = col0 + n;
            int t0   = tbase + pair*2;
            float2 v0, v1;
            v0.x = v0.y = v1.x = v1.y = 0.f;
            if (gn < N) {
                v0 = Bm[(size_t)t0*N + gn];
                v1 = Bm[(size_t)(t0+1)*N + gn];
            }
            unsigned short h0 = bf16_rn(v0.x), h1 = bf16_rn(v0.y);
            unsigned short h2 = bf16_rn(v1.x), h3 = bf16_rn(v1.y);
            unsigned short l0 = bf16_rn(v0.x - bf16_to_f(h0));
            unsigned short l1 = bf16_rn(v0.y - bf16_to_f(h1));
            unsigned short l2 = bf16_rn(v1.x - bf16_to_f(h2));
            unsigned short l3 = bf16_rn(v1.y - bf16_to_f(h3));
            int ntile = n >> 4, n0 = n & 15;
            int lrow  = (pair >> 1)*16 + n0;
            int base  = (ntile*64 + lrow)*8 + (pair & 1)*4;   // bf16 units, 8B-aligned
            uint2 hp, lp;
            hp.x = (unsigned)h0 | ((unsigned)h1 << 16);
            hp.y = (unsigned)h2 | ((unsigned)h3 << 16);
            lp.x = (unsigned)l0 | ((unsigned)l1 << 16);
            lp.y = (unsigned)l2 | ((unsigned)l3 << 16);
            *(uint2*)&BhS[base] = hp;
            *(uint2*)&BlS[base] = lp;
        }
        __syncthreads();
        // ---- A fragments direct from global (L2-resident) ----
        short8 Ah[2], Al[2];
#pragma unroll
        for (int mi = 0; mi < 2; ++mi) {
            size_t aoff = (size_t)(arow0 + mi*16)*KP + kt + lq*8;
            Ah[mi] = *(const short8*)(EH + aoff);
            Al[mi] = *(const short8*)(EL + aoff);
        }
#pragma unroll
        for (int nj = 0; nj < 4; ++nj) {
            short8 Bh = *(const short8*)&BhS[(nj*64 + lane)*8];
            short8 Bl = *(const short8*)&BlS[(nj*64 + lane)*8];
#pragma unroll
            for (int mi = 0; mi < 2; ++mi) {
                acc[mi][nj] = __builtin_amdgcn_mfma_f32_16x16x32_bf16(Ah[mi], Bh, acc[mi][nj], 0, 0, 0);
                acc[mi][nj] = __builtin_amdgcn_mfma_f32_16x16x32_bf16(Ah[mi], Bl, acc[mi][nj], 0, 0, 0);
                acc[mi][nj] = __builtin_amdgcn_mfma_f32_16x16x32_bf16(Al[mi], Bh, acc[mi][nj], 0, 0, 0);
            }
        }
        __syncthreads();
    }
    // epilogue: D row = quad*4+reg, col = lane&15; stacked row -> (m = row>>1, comp = row&1)
#pragma unroll
    for (int mi = 0; mi < 2; ++mi) {
#pragma unroll
        for (int nj = 0; nj < 4; ++nj) {
            int coln = col0 + nj*16 + lm;
            if (coln < N) {
#pragma unroll
                for (int r = 0; r < 4; ++r) {
                    int row = row0 + wave*32 + mi*16 + lq*4 + r;
                    Cm[((size_t)(row >> 1)*N + coln)*2 + (row & 1)] = acc[mi][nj][r];
                }
            }
        }
    }
}

// ---------------- row pass C2R (round-3 64x64 tile, 4x4 micro) ----------------
__global__ __launch_bounds__(256) void c2r_row(
    const float2* __restrict__ Ain, const float2* __restrict__ Ui,
    float* __restrict__ outp, int B)
{
    __shared__ float2 As[16][65];
    __shared__ float2 Bs[16][66];
    int row0 = blockIdx.y * 64, col0 = blockIdx.x * 64;
    int tid = threadIdx.x, tx = tid & 15, ty = tid >> 4;
    float acc[4][4];
#pragma unroll
    for (int i = 0; i < 4; i++)
#pragma unroll
        for (int j = 0; j < 4; j++) acc[i][j] = 0.f;
    for (int kt = 0; kt < KF; kt += 16) {
#pragma unroll
        for (int l = 0; l < 4; l++) {
            int i = tid + l*256;
            int m = i >> 4, kk = i & 15;
            int gk = kt + kk;
            float2 v; v.x = 0.f; v.y = 0.f;
            if (gk < KF) v = Ain[(size_t)(row0+m)*KF + gk];
            As[kk][m] = v;
        }
#pragma unroll
        for (int l = 0; l < 4; l++) {
            int i = tid + l*256;
            int kk = i >> 6, nn = i & 63;
            int gk = kt + kk;
            float2 v; v.x = 0.f; v.y = 0.f;
            if (gk < KF) v = Ui[(size_t)gk*FH + col0 + nn];
            Bs[kk][nn] = v;
        }
        __syncthreads();
#pragma unroll
        for (int kk = 0; kk < 16; kk++) {
            float2 a[4], b[4];
#pragma unroll
            for (int i = 0; i < 4; i++) a[i] = As[kk][ty*4+i];
#pragma unroll
            for (int j = 0; j < 4; j++) b[j] = Bs[kk][tx + 16*j];
#pragma unroll
            for (int i = 0; i < 4; i++)
#pragma unroll
                for (int j = 0; j < 4; j++)
                    acc[i][j] += a[i].x*b[j].x + a[i].y*b[j].y;
        }
        __syncthreads();
    }
#pragma unroll
    for (int i = 0; i < 4; i++) {
        int gm = row0 + ty*4 + i;
        int y = gm / B, bi = gm - y*B;
#pragma unroll
        for (int j = 0; j < 4; j++)
            outp[((size_t)bi*FH + y)*FH + col0 + tx + 16*j] = acc[i][j];
    }
}

// ---------------- elementwise frequency-domain updates (G images) ----------------
__global__ void fg_kernel(const float2* __restrict__ Ffy, const float2* __restrict__ Fz,
                          const float2* __restrict__ Fk, const float* __restrict__ zetas,
                          int L, int total, float2* __restrict__ Fg)
{
    int idx = blockIdx.x*256 + threadIdx.x;
    if (idx >= total) return;
    int k = idx % KF; int r = idx / KF;
    int c = r & 15; int hi = r >> 4;     // hi = h*G + img
    float zeta = 10.f * zetas[L*16 + c];
    float2 fk = Fk[(size_t)hi*KF + k];
    float2 fy = Ffy[idx];
    float2 fz = Fz[idx];
    float nx = zeta*(fk.x*fy.x + fk.y*fy.y) + fz.x;
    float ny = zeta*(fk.x*fy.y - fk.y*fy.x) + fz.y;
    float den = zeta*(fk.x*fk.x + fk.y*fk.y) + 1.f + 1e-8f;
    float inv = 1.f/den;
    float2 o; o.x = nx*inv; o.y = ny*inv;
    Fg[idx] = o;
}

__global__ void knum_kernel(const float2* __restrict__ Fz, const float2* __restrict__ Ffy,
                            const float2* __restrict__ Fk, const float* __restrict__ kprox,
                            int L, int total, float2* __restrict__ outk)
{
    int idx = blockIdx.x*256 + threadIdx.x;
    if (idx >= total) return;
    int k = idx % KF; int r = idx / KF;  // r = h*G + img
    float zk = kprox[L];
    float s1x = 0.f, s1y = 0.f, s2 = 0.f;
    for (int c = 0; c < 16; ++c) {
        size_t bi = ((size_t)r*16 + c)*KF + k;
        float2 fz = Fz[bi], fy = Ffy[bi];
        s1x += fz.x*fy.x + fz.y*fy.y;
        s1y += fz.x*fy.y - fz.y*fy.x;
        s2  += fz.x*fz.x + fz.y*fz.y;
    }
    float2 fk = Fk[idx];
    float nx = zk*s1x + fk.x, ny = zk*s1y + fk.y;
    float den = zk*s2 + 1.f + 1e-8f;
    float inv = 1.f/den;
    float2 o; o.x = nx*inv; o.y = ny*inv;
    outk[idx] = o;
}

// ---------------- kernel (blur-kernel) update ----------------
__device__ __forceinline__ void lse_comb(float& m, float& s, float m2, float s2)
{
    if (m2 > m) { s = s * expf(m - m2) + s2; m = m2; }
    else        { s = s + s2 * expf(m2 - m); }
}

__global__ __launch_bounds__(256) void lse_part_kernel(const float* __restrict__ kraw0,
                                                       float2* __restrict__ parts)
{
    int img = blockIdx.y;
    const float* kraw = kraw0 + (size_t)img*FH*FH;
    int b = blockIdx.x, t = threadIdx.x;
    float m = -1e30f, s = 0.f;
    for (int i = b*256 + t; i < FH*FH; i += 64*256) {
        float v = 100.f * kraw[i];
        lse_comb(m, s, v, 1.f);
    }
    __shared__ float sm[256], ss[256];
    sm[t] = m; ss[t] = s;
    __syncthreads();
    for (int st = 128; st > 0; st >>= 1) {
        if (t < st) {
            float mm = sm[t], sc = ss[t];
            lse_comb(mm, sc, sm[t+st], ss[t+st]);
            sm[t] = mm; ss[t] = sc;
        }
        __syncthreads();
    }
    if (t == 0) { float2 o; o.x = sm[0]; o.y = ss[0]; parts[img*64 + b] = o; }
}

__global__ void lse_final_kernel(const float2* __restrict__ parts, float* __restrict__ kmaxB)
{
    int img = blockIdx.x;
    int t = threadIdx.x;
    __shared__ float sm[64], ss[64];
    float2 p = parts[img*64 + t];
    sm[t] = p.x; ss[t] = p.y;
    __syncthreads();
    for (int st = 32; st > 0; st >>= 1) {
        if (t < st) {
            float mm = sm[t], sc = ss[t];
            lse_comb(mm, sc, sm[t+st], ss[t+st]);
            sm[t] = mm; ss[t] = sc;
        }
        __syncthreads();
    }
    if (t == 0) kmaxB[img] = (sm[0] + logf(ss[0])) * 0.01f;
}

__global__ void zero_kernel(float* __restrict__ p, int n)
{
    int i = blockIdx.x*256 + threadIdx.x;
    if (i < n) p[i] = 0.f;
}

__global__ void kdelta_kernel(float* __restrict__ kful, int G)
{
    int t = threadIdx.x;
    if (t < G) kful[(size_t)t*FH*FH + 22*FH + 22] = 1.f;
}

__global__ __launch_bounds__(256) void knew_kernel(const float* __restrict__ kraw0,
    const float* __restrict__ kmax, const float* __restrict__ kb, int L,
    float* __restrict__ kful0)
{
    int img = blockIdx.x;
    const float* kraw = kraw0 + (size_t)img*FH*FH;
    float*       kful = kful0 + (size_t)img*FH*FH;
    int t = threadIdx.x;
    float thr = 0.01f * kb[L] * kmax[img];
    float vs[8]; float loc = 0.f;
#pragma unroll
    for (int ii = 0; ii < 8; ++ii) {
        int i = t + ii*256;
        float v = 0.f;
        if (i < 45*45) {
            int y = i/45, x = i - y*45;
            v = fmaxf(kraw[y*FH + x] - thr, 0.f);
        }
        vs[ii] = v; loc += v;
    }
    __shared__ float sr[256];
    sr[t] = loc; __syncthreads();
    for (int st = 128; st > 0; st >>= 1) { if (t < st) sr[t] += sr[t+st]; __syncthreads(); }
    float den = sr[0] + 1e-8f;
#pragma unroll
    for (int ii = 0; ii < 8; ++ii) {
        int i = t + ii*256;
        if (i < 45*45) {
            int y = i/45, x = i - y*45;
            float v = vs[ii] + ((y == 22 && x == 22) ? 1e-8f : 0.f);
            kful[y*FH + x] = v / den;
        }
    }
}

// ---------------- Fw0 (direct 9-term DFT of shifted 3x3), image-independent ----------------
__global__ void fw0_kernel(const float* __restrict__ w0c, const float2* __restrict__ Ef,
                           float2* __restrict__ Fw0)
{
    int idx = blockIdx.x*256 + threadIdx.x;
    if (idx >= 48*FH*KF) return;
    int k = idx % KF; int r = idx / KF;
    int c = r & 15; int r2 = r >> 4;
    int ci = r2 % 3; int h = r2 / 3;
    float accx = 0.f, accy = 0.f;
#pragma unroll
    for (int ky = 0; ky < 3; ++ky) {
        int a1 = ky - 1; if (a1 < 0) a1 += FH;
        float2 e1 = Ef[h*FH + a1];
#pragma unroll
        for (int kx = 0; kx < 3; ++kx) {
            int a2 = kx - 1; if (a2 < 0) a2 += FH;
            float2 e2 = Ef[k*FH + a2];
            float wv = w0c[((c*3 + ci)*3 + ky)*3 + kx];
            float tr = e1.x*e2.x - e1.y*e2.y;
            float ti = e1.x*e2.y + e1.y*e2.x;
            accx += wv*tr; accy += wv*ti;
        }
    }
    float2 o; o.x = accx; o.y = accy;
    Fw0[idx] = o;
}

// ---------------- final per-bin 3x3 Hermitian Wiener solve (G images) ----------------
__global__ void wiener_kernel(const float2* __restrict__ Fk, const float2* __restrict__ Fy,
    const float2* __restrict__ Fw0, const float2* __restrict__ Fg2,
    const float* __restrict__ eta, int G, int total, float2* __restrict__ Fx)
{
    int idx = blockIdx.x*256 + threadIdx.x;
    if (idx >= total) return;
    int k = idx % KF; int r = idx / KF;   // r = h*G + img
    int h = r / G;
    float2 fk = Fk[idx];
    float fksq = fk.x*fk.x + fk.y*fk.y;
    float2 fyr = Fy[((size_t)3*r + 0)*KF + k];
    float2 fyg = Fy[((size_t)3*r + 1)*KF + k];
    float2 fyb = Fy[((size_t)3*r + 2)*KF + k];
    float Crr = fksq, Cgg = fksq, Cbb = fksq;
    float2 Crg, Crb, Cgb;
    Crg.x = Crg.y = Crb.x = Crb.y = Cgb.x = Cgb.y = 0.f;
    float2 Br, Bg, Bb;
    Br.x = fk.x*fyr.x + fk.y*fyr.y; Br.y = fk.x*fyr.y - fk.y*fyr.x;
    Bg.x = fk.x*fyg.x + fk.y*fyg.y; Bg.y = fk.x*fyg.y - fk.y*fyg.x;
    Bb.x = fk.x*fyb.x + fk.y*fyb.y; Bb.y = fk.x*fyb.y - fk.y*fyb.x;
    for (int c = 0; c < 16; ++c) {
        float es = 10.f * eta[c];
        float2 wr = Fw0[((size_t)h*48 +  0 + c)*KF + k];
        float2 wg = Fw0[((size_t)h*48 + 16 + c)*KF + k];
        float2 wb = Fw0[((size_t)h*48 + 32 + c)*KF + k];
        float2 g  = Fg2[((size_t)r*16 + c)*KF + k];
        Crr += es*(wr.x*wr.x + wr.y*wr.y);
        Cgg += es*(wg.x*wg.x + wg.y*wg.y);
        Cbb += es*(wb.x*wb.x + wb.y*wb.y);
        Crg.x += es*(wr.x*wg.x + wr.y*wg.y); Crg.y += es*(wr.x*wg.y - wr.y*wg.x);
        Crb.x += es*(wr.x*wb.x + wr.y*wb.y); Crb.y += es*(wr.x*wb.y - wr.y*wb.x);
        Cgb.x += es*(wg.x*wb.x + wg.y*wb.y); Cgb.y += es*(wg.x*wb.y - wg.y*wb.x);
        Br.x += es*(wr.x*g.x + wr.y*g.y); Br.y += es*(wr.x*g.y - wr.y*g.x);
        Bg.x += es*(wg.x*g.x + wg.y*g.y); Bg.y += es*(wg.x*g.y - wg.y*g.x);
        Bb.x += es*(wb.x*g.x + wb.y*g.y); Bb.y += es*(wb.x*g.y - wb.y*g.x);
    }
    float Crg_sq = Crg.x*Crg.x + Crg.y*Crg.y;
    float Crb_sq = Crb.x*Crb.x + Crb.y*Crb.y;
    float Cgb_sq = Cgb.x*Cgb.x + Cgb.y*Cgb.y;
    float Irr = Cgg*Cbb - Cgb_sq;
    float Igg = Crr*Cbb - Crb_sq;
    float Ibb = Crr*Cgg - Crg_sq;
    float2 Irg, Irb, Igb;
    Irg.x = (Cgb.x*Crb.x + Cgb.y*Crb.y) - Cbb*Crg.x;
    Irg.y = (Cgb.x*Crb.y - Cgb.y*Crb.x) - Cbb*Crg.y;
    Irb.x = (Crg.x*Cgb.x - Crg.y*Cgb.y) - Cgg*Crb.x;
    Irb.y = (Crg.x*Cgb.y + Crg.y*Cgb.x) - Cgg*Crb.y;
    Igb.x = (Crg.x*Crb.x + Crg.y*Crb.y) - Crr*Cgb.x;
    Igb.y = (Crg.x*Crb.y - Crg.y*Crb.x) - Crr*Cgb.y;
    float tx_ = Crg.x*Cgb.x - Crg.y*Cgb.y;
    float ty_ = Crg.x*Cgb.y + Crg.y*Cgb.x;
    float den = Crr*Irr - Cgg*Crb_sq - Cbb*Crg_sq + 2.f*(tx_*Crb.x + ty_*Crb.y) + 1e-8f;
    float inv = 1.f/den;
    float2 o;
    o.x = (Irr*Br.x + (Irg.x*Bg.x - Irg.y*Bg.y) + (Irb.x*Bb.x - Irb.y*Bb.y))*inv;
    o.y = (Irr*Br.y + (Irg.x*Bg.y + Irg.y*Bg.x) + (Irb.x*Bb.y + Irb.y*Bb.x))*inv;
    Fx[((size_t)3*r + 0)*KF + k] = o;
    o.x = ((Irg.x*Br.x + Irg.y*Br.y) + Igg*Bg.x + (Igb.x*Bb.x - Igb.y*Bb.y))*inv;
    o.y = ((Irg.x*Br.y - Irg.y*Br.x) + Igg*Bg.y + (Igb.x*Bb.y + Igb.y*Bb.x))*inv;
    Fx[((size_t)3*r + 1)*KF + k] = o;
    o.x = ((Irb.x*Br.x + Irb.y*Br.y) + (Igb.x*Bg.x + Igb.y*Bg.y) + Ibb*Bb.x)*inv;
    o.y = ((Irb.x*Br.y - Irb.y*Br.x) + (Igb.x*Bg.y - Igb.y*Bg.x) + Ibb*Bb.y)*inv;
    Fx[((size_t)3*r + 2)*KF + k] = o;
}

// ---------------- output assembly (G images) ----------------
__global__ void crop_kernel(const float* __restrict__ sp, float* __restrict__ outp, int total)
{
    int idx = blockIdx.x*256 + threadIdx.x;
    if (idx >= total) return;
    int x = idx & 255; int r = idx >> 8; int y = r & 255; int plane = r >> 8;
    outp[idx] = sp[((size_t)plane*FH + (y+22))*FH + (x+22)];
}

__global__ void kcopy_kernel(const float* __restrict__ kful, float* __restrict__ outp, int total)
{
    int idx = blockIdx.x*256 + threadIdx.x;
    if (idx >= total) return;
    int rem = idx % 2025; int img = idx / 2025;
    int x = rem % 45; int y = rem / 45;
    outp[idx] = kful[(size_t)img*FH*FH + y*FH + x];
}

// =====================================================================
extern "C" void kernel_launch(void* const* d_in, const int* in_sizes, int n_in,
                              void* d_out, int out_size, void* d_ws, size_t ws_size,
                              hipStream_t stream)
{
    (void)in_sizes; (void)n_in; (void)out_size;
    const float* blurred = (const float*)d_in[0];
    const float* w0      = (const float*)d_in[1];
    const float* wsw     = (const float*)d_in[2];
    const float* biases  = (const float*)d_in[3];
    const float* kbias   = (const float*)d_in[4];
    const float* kprox   = (const float*)d_in[5];
    const float* zetas   = (const float*)d_in[6];
    const float* eta     = (const float*)d_in[7];
    float* outp = (float*)d_out;

    auto al = [](size_t b) { return (b + 255) & ~(size_t)255; };
    auto need = [&](int G) -> size_t {
        size_t s = 0;
        s += al((size_t)FH*KF*8);                 // Tf
        s += al((size_t)FH*FH*8);                 // Ef
        s += al((size_t)KF*FH*8);                 // Ui
        s += 4*al((size_t)KP*KP*2);               // EfH, EfL, EiH, EiL
        s += al(432*4);                           // w0c
        s += al((size_t)10*G*16*65536*4);         // fyN
        s += al((size_t)G*16*FH*FH*4);            // zsp
        s += 3*al((size_t)G*16*FH*KF*8);          // mid, FzFg, Ffy
        s += 3*al((size_t)G*FH*KF*8);             // Fk, kfA, kfB
        s += 2*al((size_t)G*FH*FH*4);             // kraw, kful
        s += 2*al((size_t)G*3*FH*KF*8);           // FyB, FxB
        s += al((size_t)G*64*8) + al(256);        // lseP, kmax
        return s;
    };
    int G = 4;
    while (G > 1 && need(G) > ws_size) G >>= 1;

    char* base = (char*)d_ws;
    size_t off = 0;
    auto alloc = [&](size_t bytes) -> void* {
        void* p = (void*)(base + off);
        off += (bytes + 255) & ~(size_t)255;
        return p;
    };
    float2* Tf   = (float2*)alloc((size_t)FH*KF*8);
    float2* Ef   = (float2*)alloc((size_t)FH*FH*8);
    float2* Ui   = (float2*)alloc((size_t)KF*FH*8);
    unsigned short* EfH = (unsigned short*)alloc((size_t)KP*KP*2);
    unsigned short* EfL = (unsigned short*)alloc((size_t)KP*KP*2);
    unsigned short* EiH = (unsigned short*)alloc((size_t)KP*KP*2);
    unsigned short* EiL = (unsigned short*)alloc((size_t)KP*KP*2);
    float*  w0cB = (float*)alloc(432*4);
    float*  fyN  = (float*)alloc((size_t)10*G*16*65536*4);
    float*  zsp  = (float*)alloc((size_t)G*16*FH*FH*4);
    float2* mid  = (float2*)alloc((size_t)G*16*FH*KF*8);
    float2* FzFg = (float2*)alloc((size_t)G*16*FH*KF*8);
    float2* Ffy  = (float2*)alloc((size_t)G*16*FH*KF*8);
    float2* Fk   = (float2*)alloc((size_t)G*FH*KF*8);
    float2* kfA  = (float2*)alloc((size_t)G*FH*KF*8);
    float2* kfB  = (float2*)alloc((size_t)G*FH*KF*8);
    float*  kraw = (float*)alloc((size_t)G*FH*FH*4);
    float*  kful = (float*)alloc((size_t)G*FH*FH*4);
    float2* FyB  = (float2*)alloc((size_t)G*3*FH*KF*8);
    float2* FxB  = (float2*)alloc((size_t)G*3*FH*KF*8);
    float2* lseP = (float2*)alloc((size_t)G*64*8);
    float*  kmaxB= (float*)alloc(256);
    // Fw0 (28.45 MB) overlays fyN (>= 41.9 MB even at G=1) — dead by final stage
    float2* Fw0B = (float2*)fyN;

    // tables + weight prep (image-independent)
    init_tf_k<<<(FH*KF+255)/256, 256, 0, stream>>>(Tf);
    init_ef_k<<<(FH*FH+255)/256, 256, 0, stream>>>(Ef);
    init_ui_k<<<(KF*FH+255)/256, 256, 0, stream>>>(Ui);
    init_estack<<<(KP*KP+255)/256, 256, 0, stream>>>(EfH, EfL, 0);
    init_estack<<<(KP*KP+255)/256, 256, 0, stream>>>(EiH, EiL, 1);
    w0c_kernel<<<1, 64, 0, stream>>>(w0, w0cB);

    auto zg = [&](const unsigned short* EH, const unsigned short* EL,
                  const float2* Bm, float2* Cm, int Ncols) {
        zgemm_col_mfma<<<dim3((Ncols+63)/64, (2*FH)/128), 256, 0, stream>>>(
            EH, EL, Bm, (float*)Cm, Ncols);
    };
    auto r2c = [&](const float* inp, int inH, int inW, int oY, int oX,
                   const float* thr, float2* o, int B) {
        r2c_row<<<dim3((KF+63)/64, B*FH/64), 256, 0, stream>>>(inp, inH, inW, oY, oX, thr, Tf, o, B);
    };
    auto c2r = [&](const float2* Ain, float* o, int B) {
        c2r_row<<<dim3(FH/64, B*FH/64), 256, 0, stream>>>(Ain, Ui, o, B);
    };

    const size_t IMG16 = (size_t)16*65536;        // one layer, one image
    const size_t LAY   = (size_t)G*IMG16;         // one layer, group

    for (int g0 = 0; g0 < 4; g0 += G) {
        const float* img = blurred + (size_t)g0*3*65536;

        // forward conv chain (10 checkpoints, layout [l][img*16+c][y][x])
        conv3x3_kernel<<<dim3(16,16,G), 256, 0, stream>>>(
            img, w0cB, fyN, 3, 1, (size_t)3*65536, IMG16);
        for (int l = 1; l < 10; ++l)
            conv3x3_kernel<<<dim3(16,16,G), 256, 0, stream>>>(
                fyN + (size_t)(l-1)*LAY, wsw + (size_t)(l-1)*2304,
                fyN + (size_t)l*LAY, 16, 0, IMG16, IMG16);

        // z init (circshift + threshold b0), Fz
        int totZ = G*16*FH*FH;
        zinit_kernel<<<(totZ+255)/256, 256, 0, stream>>>(fyN + 9*LAY, biases, zsp, totZ);
        r2c(zsp, FH, FH, 0, 0, nullptr, mid, G*16);
        zg(EfH, EfL, mid, FzFg, G*16*KF);

        // k init = delta
        zero_kernel<<<(G*FH*FH+255)/256, 256, 0, stream>>>(kful, G*FH*FH);
        kdelta_kernel<<<1, 64, 0, stream>>>(kful, G);

        int totS = G*16*FH*KF;   // full spectra element count
        int totK = G*FH*KF;      // kernel spectra element count
        for (int it = 0; it < 10; ++it) {
            int Lfy = 9 - it;
            r2c(fyN + (size_t)Lfy*LAY, 256, 256, 44, 44, nullptr, mid, G*16);
            zg(EfH, EfL, mid, Ffy, G*16*KF);
            r2c(kful, FH, FH, 0, 0, nullptr, mid, G);
            zg(EfH, EfL, mid, Fk, G*KF);
            fg_kernel<<<(totS+255)/256, 256, 0, stream>>>(Ffy, FzFg, Fk, zetas, it, totS, FzFg);
            zg(EiH, EiL, FzFg, mid, G*16*KF);
            c2r(mid, zsp, G*16);                    // zsp = irfft(Fg) PRE-threshold
            r2c(zsp, FH, FH, 0, 0, biases + (it+1)*16, mid, G*16);  // fused soft-threshold
            zg(EfH, EfL, mid, FzFg, G*16*KF);       // Fz_new
            knum_kernel<<<(totK+255)/256, 256, 0, stream>>>(FzFg, Ffy, Fk, kprox, it, totK, kfA);
            zg(EiH, EiL, kfA, kfB, G*KF);
            c2r(kfB, kraw, G);
            lse_part_kernel<<<dim3(64,G), 256, 0, stream>>>(kraw, lseP);
            lse_final_kernel<<<G, 64, 0, stream>>>(lseP, kmaxB);
            knew_kernel<<<G, 256, 0, stream>>>(kraw, kmaxB, kbias, it, kful);
        }

        // ---- final stage for this group ----
        r2c(img, 256, 256, 44, 44, nullptr, mid, 3*G);
        zg(EfH, EfL, mid, FyB, 3*G*KF);
        r2c(kful, FH, FH, 0, 0, nullptr, mid, G);
        zg(EfH, EfL, mid, Fk, G*KF);
        // Fg2 = rfft(softt(zsp, b_final)) — zsp holds it=9's pre-threshold irfft(Fg)
        r2c(zsp, FH, FH, 0, 0, biases + 11*16, mid, G*16);
        zg(EfH, EfL, mid, FzFg, G*16*KF);
        fw0_kernel<<<(48*FH*KF+255)/256, 256, 0, stream>>>(w0cB, Ef, Fw0B);  // overlays fyN
        wiener_kernel<<<(totK+255)/256, 256, 0, stream>>>(Fk, FyB, Fw0B, FzFg, eta, G, totK, FxB);
        zg(EiH, EiL, FxB, mid, 3*G*KF);
        c2r(mid, zsp, 3*G);
        int totC = G*3*65536;
        crop_kernel<<<(totC+255)/256, 256, 0, stream>>>(zsp, outp + (size_t)g0*3*65536, totC);
        int totKC = G*2025;
        kcopy_kernel<<<(totKC+255)/256, 256, 0, stream>>>(kful, outp + 786432 + g0*2025, totKC);
    }
}

// Round 6
// 13579.243 us; speedup vs baseline: 3.5648x; 1.1817x over previous
//
#include <hip/hip_runtime.h>
#include <math.h>

#define FH 384
#define KF 193
#define KP 768    // stacked real K' = 2*FH (col pass)
#define NR 386    // real row-spectrum width = 2*KF

typedef __attribute__((ext_vector_type(8))) short short8;
typedef __attribute__((ext_vector_type(4))) float f32x4;

static __device__ __forceinline__ float softt(float v, float b) {
    return copysignf(fmaxf(fabsf(v) - b, 0.f), v);
}
static __device__ __forceinline__ unsigned short bf16_rn(float v) {
    unsigned u = __float_as_uint(v);
    unsigned r = (u + 0x7FFFu + ((u >> 16) & 1u)) >> 16;
    return (unsigned short)r;
}
static __device__ __forceinline__ float bf16_to_f(unsigned short h) {
    return __uint_as_float(((unsigned)h) << 16);
}

// ---------------- tables ----------------
__global__ void init_ef_k(float2* Ef) {
    int idx = blockIdx.x * 256 + threadIdx.x;
    if (idx >= FH * FH) return;
    int h = idx / FH, j = idx % FH;
    int m = (h * j) % FH;
    float th = (float)(6.283185307179586 / FH) * (float)m;
    float2 v; v.x = cosf(th); v.y = -sinf(th);
    Ef[idx] = v;
}

// stacked real DFT matrix for MFMA col pass (A-operand), bf16 hi/lo
__global__ void init_estack(unsigned short* __restrict__ H, unsigned short* __restrict__ L, int inv)
{
    int idx = blockIdx.x * 256 + threadIdx.x;
    if (idx >= KP * KP) return;
    int gm = idx / KP, kp = idx % KP;
    int m = gm >> 1, comp = gm & 1;
    int t = kp >> 1, ri = kp & 1;
    int mm = (m * t) % FH;
    float th = (float)(6.283185307179586 / FH) * (float)mm;
    float c = cosf(th), s = sinf(th);
    float er, ei;
    if (inv) { er = c * (1.f/FH); ei = s * (1.f/FH); }
    else     { er = c;            ei = -s; }
    float v;
    if (comp == 0) v = (ri == 0) ? er : -ei;
    else           v = (ri == 0) ? ei :  er;
    unsigned short h = bf16_rn(v);
    H[idx] = h;
    L[idx] = bf16_rn(v - bf16_to_f(h));
}

// r2c row-pass B-table, transposed: Tt[n][w], n=2*kf+ri (448 rows, zero pad), w in [0,384)
__global__ void init_tt(unsigned short* __restrict__ H, unsigned short* __restrict__ L)
{
    int idx = blockIdx.x * 256 + threadIdx.x;
    if (idx >= 448 * FH) return;
    int n = idx / FH, w = idx % FH;
    float v = 0.f;
    if (n < NR) {
        int kf = n >> 1, ri = n & 1;
        int m = (w * kf) % FH;
        float th = (float)(6.283185307179586 / FH) * (float)m;
        v = ri ? -sinf(th) : cosf(th);
    }
    unsigned short h = bf16_rn(v);
    H[idx] = h;
    L[idx] = bf16_rn(v - bf16_to_f(h));
}

// c2r row-pass B-table, transposed: Ut[x][kp], kp=2*k+ri (416 cols, zero pad)
__global__ void init_ut(unsigned short* __restrict__ H, unsigned short* __restrict__ L)
{
    int idx = blockIdx.x * 256 + threadIdx.x;
    if (idx >= FH * 416) return;
    int x = idx / 416, kp = idx % 416;
    float v = 0.f;
    if (kp < NR) {
        int k = kp >> 1, ri = kp & 1;
        float ck = (k == 0 || k == FH/2) ? (1.f/FH) : (2.f/FH);
        int m = (k * x) % FH;
        float th = (float)(6.283185307179586 / FH) * (float)m;
        v = ri ? -ck*sinf(th) : ck*cosf(th);
    }
    unsigned short h = bf16_rn(v);
    H[idx] = h;
    L[idx] = bf16_rn(v - bf16_to_f(h));
}

// ---------------- w0 centering ----------------
__global__ void w0c_kernel(const float* __restrict__ w0, float* __restrict__ w0c) {
    int t = threadIdx.x;
    if (t < 48) {
        float m = 0.f;
        for (int d = 0; d < 9; ++d) m += w0[t*9+d];
        m *= (1.f/9.f);
        for (int d = 0; d < 9; ++d) w0c[t*9+d] = w0[t*9+d] - m;
    }
}

// ---------------- 3x3 conv (XLA cross-correlation, SAME), blockIdx.z = image ----------------
__global__ __launch_bounds__(256) void conv3x3_kernel(
    const float* __restrict__ inp0, const float* __restrict__ w,
    float* __restrict__ outp0, int Cin, int flip,
    size_t inImgStride, size_t outImgStride)
{
    const float* inp  = inp0  + (size_t)blockIdx.z * inImgStride;
    float*       outp = outp0 + (size_t)blockIdx.z * outImgStride;
    __shared__ float tile[18][19];
    __shared__ float wl[16*16*9];
    int x0 = blockIdx.x * 16, y0 = blockIdx.y * 16;
    int t = threadIdx.x;
    int tx = t & 15, ty = t >> 4;
    int nw = 16 * Cin * 9;
    for (int i = t; i < nw; i += 256) {
        int d = i % 9;
        wl[i] = flip ? w[i + 8 - 2*d] : w[i];
    }
    float acc[16];
#pragma unroll
    for (int co = 0; co < 16; ++co) acc[co] = 0.f;
    for (int ci = 0; ci < Cin; ++ci) {
        __syncthreads();
        for (int i = t; i < 18*18; i += 256) {
            int yy = i / 18, xx = i % 18;
            int gy = y0 - 1 + yy, gx = x0 - 1 + xx;
            float v = 0.f;
            if (gy >= 0 && gy < 256 && gx >= 0 && gx < 256)
                v = inp[((size_t)ci*256 + gy)*256 + gx];
            tile[yy][xx] = v;
        }
        __syncthreads();
        float v[9];
#pragma unroll
        for (int dy = 0; dy < 3; dy++)
#pragma unroll
            for (int dx = 0; dx < 3; dx++) v[dy*3+dx] = tile[ty+dy][tx+dx];
#pragma unroll
        for (int co = 0; co < 16; co++) {
            const float* wp = &wl[(co*Cin+ci)*9];
            acc[co] += v[0]*wp[0]+v[1]*wp[1]+v[2]*wp[2]
                     + v[3]*wp[3]+v[4]*wp[4]+v[5]*wp[5]
                     + v[6]*wp[6]+v[7]*wp[7]+v[8]*wp[8];
        }
    }
#pragma unroll
    for (int co = 0; co < 16; co++)
        outp[((size_t)co*256 + (y0+ty))*256 + (x0+tx)] = acc[co];
}

// ---------------- z init: circshift(22,22) of padded fy9 + soft threshold ------
__global__ void zinit_kernel(const float* __restrict__ fy9, const float* __restrict__ b0,
                             float* __restrict__ z, int total)
{
    int idx = blockIdx.x*256 + threadIdx.x;
    if (idx >= total) return;
    int x = idx % FH; int r = idx / FH; int y = r % FH; int plane = r / FH;
    int c = plane & 15;
    int Y = y + 22; if (Y >= FH) Y -= FH;
    int X = x + 22; if (X >= FH) X -= FH;
    int yy = Y - 44, xx = X - 44;
    float v = 0.f;
    if (yy >= 0 && yy < 256 && xx >= 0 && xx < 256)
        v = fy9[((size_t)plane*256 + yy)*256 + xx];
    z[idx] = softt(v, b0[c]);
}

// ---------------- MFMA row pass R2C: out[(y*B+plane)*386 + n] = sum_w data*Tt ----------------
// grid (7, 3, B). Data staged as A-frags (hi/lo, fused softt); table = B-operand from global.
__global__ __launch_bounds__(256) void r2c_row_mfma(
    const float* __restrict__ inp, int inH, int inW, int offY, int offX,
    const float* __restrict__ thr,
    const unsigned short* __restrict__ TtH, const unsigned short* __restrict__ TtL,
    float* __restrict__ outp, int B)
{
    __shared__ unsigned short AhS[8*64*8];
    __shared__ unsigned short AlS[8*64*8];
    int col0 = blockIdx.x * 64;
    int y0   = blockIdx.y * 128;
    int plane = blockIdx.z;
    int tid = threadIdx.x;
    int wave = tid >> 6, lane = tid & 63;
    int lm = lane & 15, lq = lane >> 4;
    f32x4 acc[2][4];
#pragma unroll
    for (int mi = 0; mi < 2; ++mi)
#pragma unroll
        for (int nj = 0; nj < 4; ++nj) acc[mi][nj] = (f32x4){0.f,0.f,0.f,0.f};
    float bthr = thr ? thr[plane & 15] : 0.f;
    const float* inpP = inp + (size_t)plane*inH*inW;
    int ktlo = (offX >> 5) << 5;
    int kthi = offX + inW;
    for (int kt = ktlo; kt < kthi; kt += 32) {
        // stage 128 rows x 32 k, hi/lo, fragment order
#pragma unroll
        for (int s = 0; s < 4; ++s) {
            int slot = tid + s*256;
            int r = slot >> 3, kq = slot & 7;
            int yy = y0 + r - offY;
            float v[4];
#pragma unroll
            for (int d = 0; d < 4; ++d) {
                int xx = kt + kq*4 + d - offX;
                float t = 0.f;
                if (yy >= 0 && yy < inH && xx >= 0 && xx < inW)
                    t = inpP[(size_t)yy*inW + xx];
                if (thr) t = softt(t, bthr);
                v[d] = t;
            }
            unsigned short h0 = bf16_rn(v[0]), h1 = bf16_rn(v[1]);
            unsigned short h2 = bf16_rn(v[2]), h3 = bf16_rn(v[3]);
            unsigned short l0 = bf16_rn(v[0] - bf16_to_f(h0));
            unsigned short l1 = bf16_rn(v[1] - bf16_to_f(h1));
            unsigned short l2 = bf16_rn(v[2] - bf16_to_f(h2));
            unsigned short l3 = bf16_rn(v[3] - bf16_to_f(h3));
            int base = ((r >> 4)*64 + (r & 15) + 16*(kq >> 1))*8 + (kq & 1)*4;
            uint2 hp, lp;
            hp.x = (unsigned)h0 | ((unsigned)h1 << 16);
            hp.y = (unsigned)h2 | ((unsigned)h3 << 16);
            lp.x = (unsigned)l0 | ((unsigned)l1 << 16);
            lp.y = (unsigned)l2 | ((unsigned)l3 << 16);
            *(uint2*)&AhS[base] = hp;
            *(uint2*)&AlS[base] = lp;
        }
        __syncthreads();
        short8 Ah[2], Al[2];
#pragma unroll
        for (int mi = 0; mi < 2; ++mi) {
            Ah[mi] = *(const short8*)&AhS[((wave*2 + mi)*64 + lane)*8];
            Al[mi] = *(const short8*)&AlS[((wave*2 + mi)*64 + lane)*8];
        }
#pragma unroll
        for (int nj = 0; nj < 4; ++nj) {
            size_t toff = (size_t)(col0 + nj*16 + lm)*FH + kt + lq*8;
            short8 Bh = *(const short8*)(TtH + toff);
            short8 Bl = *(const short8*)(TtL + toff);
#pragma unroll
            for (int mi = 0; mi < 2; ++mi) {
                acc[mi][nj] = __builtin_amdgcn_mfma_f32_16x16x32_bf16(Ah[mi], Bh, acc[mi][nj], 0, 0, 0);
                acc[mi][nj] = __builtin_amdgcn_mfma_f32_16x16x32_bf16(Ah[mi], Bl, acc[mi][nj], 0, 0, 0);
                acc[mi][nj] = __builtin_amdgcn_mfma_f32_16x16x32_bf16(Al[mi], Bh, acc[mi][nj], 0, 0, 0);
            }
        }
        __syncthreads();
    }
#pragma unroll
    for (int mi = 0; mi < 2; ++mi) {
#pragma unroll
        for (int nj = 0; nj < 4; ++nj) {
            int n = col0 + nj*16 + lm;
            if (n < NR) {
#pragma unroll
                for (int rr = 0; rr < 4; ++rr) {
                    int y = y0 + wave*32 + mi*16 + lq*4 + rr;
                    outp[((size_t)y*B + plane)*NR + n] = acc[mi][nj][rr];
                }
            }
        }
    }
}

// ---------------- MFMA row pass C2R: out[plane][y][x] = sum_kp A'[y*B+plane][kp]*Ut[x][kp] --
// grid (6, 3, B). A' = real view of spectrum rows (386 wide); Ut padded to 416.
__global__ __launch_bounds__(256) void c2r_row_mfma(
    const float* __restrict__ Aflat,
    const unsigned short* __restrict__ UtH, const unsigned short* __restrict__ UtL,
    float* __restrict__ outp, int B)
{
    __shared__ unsigned short AhS[8*64*8];
    __shared__ unsigned short AlS[8*64*8];
    int col0 = blockIdx.x * 64;
    int y0   = blockIdx.y * 128;
    int plane = blockIdx.z;
    int tid = threadIdx.x;
    int wave = tid >> 6, lane = tid & 63;
    int lm = lane & 15, lq = lane >> 4;
    f32x4 acc[2][4];
#pragma unroll
    for (int mi = 0; mi < 2; ++mi)
#pragma unroll
        for (int nj = 0; nj < 4; ++nj) acc[mi][nj] = (f32x4){0.f,0.f,0.f,0.f};
    for (int kt = 0; kt < 416; kt += 32) {
#pragma unroll
        for (int s = 0; s < 4; ++s) {
            int slot = tid + s*256;
            int r = slot >> 3, kq = slot & 7;
            size_t rowb = ((size_t)(y0 + r)*B + plane)*NR;
            float v[4];
#pragma unroll
            for (int d = 0; d < 4; ++d) {
                int kp = kt + kq*4 + d;
                v[d] = (kp < NR) ? Aflat[rowb + kp] : 0.f;
            }
            unsigned short h0 = bf16_rn(v[0]), h1 = bf16_rn(v[1]);
            unsigned short h2 = bf16_rn(v[2]), h3 = bf16_rn(v[3]);
            unsigned short l0 = bf16_rn(v[0] - bf16_to_f(h0));
            unsigned short l1 = bf16_rn(v[1] - bf16_to_f(h1));
            unsigned short l2 = bf16_rn(v[2] - bf16_to_f(h2));
            unsigned short l3 = bf16_rn(v[3] - bf16_to_f(h3));
            int base = ((r >> 4)*64 + (r & 15) + 16*(kq >> 1))*8 + (kq & 1)*4;
            uint2 hp, lp;
            hp.x = (unsigned)h0 | ((unsigned)h1 << 16);
            hp.y = (unsigned)h2 | ((unsigned)h3 << 16);
            lp.x = (unsigned)l0 | ((unsigned)l1 << 16);
            lp.y = (unsigned)l2 | ((unsigned)l3 << 16);
            *(uint2*)&AhS[base] = hp;
            *(uint2*)&AlS[base] = lp;
        }
        __syncthreads();
        short8 Ah[2], Al[2];
#pragma unroll
        for (int mi = 0; mi < 2; ++mi) {
            Ah[mi] = *(const short8*)&AhS[((wave*2 + mi)*64 + lane)*8];
            Al[mi] = *(const short8*)&AlS[((wave*2 + mi)*64 + lane)*8];
        }
#pragma unroll
        for (int nj = 0; nj < 4; ++nj) {
            size_t toff = (size_t)(col0 + nj*16 + lm)*416 + kt + lq*8;
            short8 Bh = *(const short8*)(UtH + toff);
            short8 Bl = *(const short8*)(UtL + toff);
#pragma unroll
            for (int mi = 0; mi < 2; ++mi) {
                acc[mi][nj] = __builtin_amdgcn_mfma_f32_16x16x32_bf16(Ah[mi], Bh, acc[mi][nj], 0, 0, 0);
                acc[mi][nj] = __builtin_amdgcn_mfma_f32_16x16x32_bf16(Ah[mi], Bl, acc[mi][nj], 0, 0, 0);
                acc[mi][nj] = __builtin_amdgcn_mfma_f32_16x16x32_bf16(Al[mi], Bh, acc[mi][nj], 0, 0, 0);
            }
        }
        __syncthreads();
    }
#pragma unroll
    for (int mi = 0; mi < 2; ++mi) {
#pragma unroll
        for (int nj = 0; nj < 4; ++nj) {
            int x = col0 + nj*16 + lm;
#pragma unroll
            for (int rr = 0; rr < 4; ++rr) {
                int y = y0 + wave*32 + mi*16 + lq*4 + rr;
                outp[((size_t)plane*FH + y)*FH + x] = acc[mi][nj][rr];
            }
        }
    }
}

// ---------------- MFMA col pass: C = E·B (complex), stacked-real bf16x3 ----------------
__global__ __launch_bounds__(256) void zgemm_col_mfma(
    const unsigned short* __restrict__ EH, const unsigned short* __restrict__ EL,
    const float2* __restrict__ Bm, float* __restrict__ Cm, int N)
{
    __shared__ unsigned short BhS[4*64*8];
    __shared__ unsigned short BlS[4*64*8];
    int col0 = blockIdx.x * 64;
    int row0 = blockIdx.y * 128;
    int tid = threadIdx.x;
    int wave = tid >> 6, lane = tid & 63;
    int lm = lane & 15, lq = lane >> 4;
    f32x4 acc[2][4];
#pragma unroll
    for (int mi = 0; mi < 2; ++mi)
#pragma unroll
        for (int nj = 0; nj < 4; ++nj) acc[mi][nj] = (f32x4){0.f,0.f,0.f,0.f};
    int arow0 = row0 + wave*32 + lm;
    for (int kt = 0; kt < KP; kt += 32) {
        int tbase = kt >> 1;
#pragma unroll
        for (int s = 0; s < 2; ++s) {
            int slot = tid + s*256;
            int pair = slot >> 6;
            int n    = slot & 63;
            int gn   = col0 + n;
            int t0   = tbase + pair*2;
            float2 v0, v1;
            v0.x = v0.y = v1.x = v1.y = 0.f;
            if (gn < N) {
                v0 = Bm[(size_t)t0*N + gn];
                v1 = Bm[(size_t)(t0+1)*N + gn];
            }
            unsigned short h0 = bf16_rn(v0.x), h1 = bf16_rn(v0.y);
            unsigned short h2 = bf16_rn(v1.x), h3 = bf16_rn(v1.y);
            unsigned short l0 = bf16_rn(v0.x - bf16_to_f(h0));
            unsigned short l1 = bf16_rn(v0.y - bf16_to_f(h1));
            unsigned short l2 = bf16_rn(v1.x - bf16_to_f(h2));
            unsigned short l3 = bf16_rn(v1.y - bf16_to_f(h3));
            int ntile = n >> 4, n0 = n & 15;
            int lrow  = (pair >> 1)*16 + n0;
            int base  = (ntile*64 + lrow)*8 + (pair & 1)*4;
            uint2 hp, lp;
            hp.x = (unsigned)h0 | ((unsigned)h1 << 16);
            hp.y = (unsigned)h2 | ((unsigned)h3 << 16);
            lp.x = (unsigned)l0 | ((unsigned)l1 << 16);
            lp.y = (unsigned)l2 | ((unsigned)l3 << 16);
            *(uint2*)&BhS[base] = hp;
            *(uint2*)&BlS[base] = lp;
        }
        __syncthreads();
        short8 Ah[2], Al[2];
#pragma unroll
        for (int mi = 0; mi < 2; ++mi) {
            size_t aoff = (size_t)(arow0 + mi*16)*KP + kt + lq*8;
            Ah[mi] = *(const short8*)(EH + aoff);
            Al[mi] = *(const short8*)(EL + aoff);
        }
#pragma unroll
        for (int nj = 0; nj < 4; ++nj) {
            short8 Bh = *(const short8*)&BhS[(nj*64 + lane)*8];
            short8 Bl = *(const short8*)&BlS[(nj*64 + lane)*8];
#pragma unroll
            for (int mi = 0; mi < 2; ++mi) {
                acc[mi][nj] = __builtin_amdgcn_mfma_f32_16x16x32_bf16(Ah[mi], Bh, acc[mi][nj], 0, 0, 0);
                acc[mi][nj] = __builtin_amdgcn_mfma_f32_16x16x32_bf16(Ah[mi], Bl, acc[mi][nj], 0, 0, 0);
                acc[mi][nj] = __builtin_amdgcn_mfma_f32_16x16x32_bf16(Al[mi], Bh, acc[mi][nj], 0, 0, 0);
            }
        }
        __syncthreads();
    }
#pragma unroll
    for (int mi = 0; mi < 2; ++mi) {
#pragma unroll
        for (int nj = 0; nj < 4; ++nj) {
            int coln = col0 + nj*16 + lm;
            if (coln < N) {
#pragma unroll
                for (int r = 0; r < 4; ++r) {
                    int row = row0 + wave*32 + mi*16 + lq*4 + r;
                    Cm[((size_t)(row >> 1)*N + coln)*2 + (row & 1)] = acc[mi][nj][r];
                }
            }
        }
    }
}

// ---------------- elementwise frequency-domain updates (G images) ----------------
__global__ void fg_kernel(const float2* __restrict__ Ffy, const float2* __restrict__ Fz,
                          const float2* __restrict__ Fk, const float* __restrict__ zetas,
                          int L, int total, float2* __restrict__ Fg)
{
    int idx = blockIdx.x*256 + threadIdx.x;
    if (idx >= total) return;
    int k = idx % KF; int r = idx / KF;
    int c = r & 15; int hi = r >> 4;
    float zeta = 10.f * zetas[L*16 + c];
    float2 fk = Fk[(size_t)hi*KF + k];
    float2 fy = Ffy[idx];
    float2 fz = Fz[idx];
    float nx = zeta*(fk.x*fy.x + fk.y*fy.y) + fz.x;
    float ny = zeta*(fk.x*fy.y - fk.y*fy.x) + fz.y;
    float den = zeta*(fk.x*fk.x + fk.y*fk.y) + 1.f + 1e-8f;
    float inv = 1.f/den;
    float2 o; o.x = nx*inv; o.y = ny*inv;
    Fg[idx] = o;
}

__global__ void knum_kernel(const float2* __restrict__ Fz, const float2* __restrict__ Ffy,
                            const float2* __restrict__ Fk, const float* __restrict__ kprox,
                            int L, int total, float2* __restrict__ outk)
{
    int idx = blockIdx.x*256 + threadIdx.x;
    if (idx >= total) return;
    int k = idx % KF; int r = idx / KF;
    float zk = kprox[L];
    float s1x = 0.f, s1y = 0.f, s2 = 0.f;
    for (int c = 0; c < 16; ++c) {
        size_t bi = ((size_t)r*16 + c)*KF + k;
        float2 fz = Fz[bi], fy = Ffy[bi];
        s1x += fz.x*fy.x + fz.y*fy.y;
        s1y += fz.x*fy.y - fz.y*fy.x;
        s2  += fz.x*fz.x + fz.y*fz.y;
    }
    float2 fk = Fk[idx];
    float nx = zk*s1x + fk.x, ny = zk*s1y + fk.y;
    float den = zk*s2 + 1.f + 1e-8f;
    float inv = 1.f/den;
    float2 o; o.x = nx*inv; o.y = ny*inv;
    outk[idx] = o;
}

// ---------------- kernel (blur-kernel) update ----------------
__device__ __forceinline__ void lse_comb(float& m, float& s, float m2, float s2)
{
    if (m2 > m) { s = s * expf(m - m2) + s2; m = m2; }
    else        { s = s + s2 * expf(m2 - m); }
}

__global__ __launch_bounds__(256) void lse_part_kernel(const float* __restrict__ kraw0,
                                                       float2* __restrict__ parts)
{
    int img = blockIdx.y;
    const float* kraw = kraw0 + (size_t)img*FH*FH;
    int b = blockIdx.x, t = threadIdx.x;
    float m = -1e30f, s = 0.f;
    for (int i = b*256 + t; i < FH*FH; i += 64*256) {
        float v = 100.f * kraw[i];
        lse_comb(m, s, v, 1.f);
    }
    __shared__ float sm[256], ss[256];
    sm[t] = m; ss[t] = s;
    __syncthreads();
    for (int st = 128; st > 0; st >>= 1) {
        if (t < st) {
            float mm = sm[t], sc = ss[t];
            lse_comb(mm, sc, sm[t+st], ss[t+st]);
            sm[t] = mm; ss[t] = sc;
        }
        __syncthreads();
    }
    if (t == 0) { float2 o; o.x = sm[0]; o.y = ss[0]; parts[img*64 + b] = o; }
}

__global__ void lse_final_kernel(const float2* __restrict__ parts, float* __restrict__ kmaxB)
{
    int img = blockIdx.x;
    int t = threadIdx.x;
    __shared__ float sm[64], ss[64];
    float2 p = parts[img*64 + t];
    sm[t] = p.x; ss[t] = p.y;
    __syncthreads();
    for (int st = 32; st > 0; st >>= 1) {
        if (t < st) {
            float mm = sm[t], sc = ss[t];
            lse_comb(mm, sc, sm[t+st], ss[t+st]);
            sm[t] = mm; ss[t] = sc;
        }
        __syncthreads();
    }
    if (t == 0) kmaxB[img] = (sm[0] + logf(ss[0])) * 0.01f;
}

__global__ void zero_kernel(float* __restrict__ p, int n)
{
    int i = blockIdx.x*256 + threadIdx.x;
    if (i < n) p[i] = 0.f;
}

__global__ void kdelta_kernel(float* __restrict__ kful, int G)
{
    int t = threadIdx.x;
    if (t < G) kful[(size_t)t*FH*FH + 22*FH + 22] = 1.f;
}

__global__ __launch_bounds__(256) void knew_kernel(const float* __restrict__ kraw0,
    const float* __restrict__ kmax, const float* __restrict__ kb, int L,
    float* __restrict__ kful0)
{
    int img = blockIdx.x;
    const float* kraw = kraw0 + (size_t)img*FH*FH;
    float*       kful = kful0 + (size_t)img*FH*FH;
    int t = threadIdx.x;
    float thr = 0.01f * kb[L] * kmax[img];
    float vs[8]; float loc = 0.f;
#pragma unroll
    for (int ii = 0; ii < 8; ++ii) {
        int i = t + ii*256;
        float v = 0.f;
        if (i < 45*45) {
            int y = i/45, x = i - y*45;
            v = fmaxf(kraw[y*FH + x] - thr, 0.f);
        }
        vs[ii] = v; loc += v;
    }
    __shared__ float sr[256];
    sr[t] = loc; __syncthreads();
    for (int st = 128; st > 0; st >>= 1) { if (t < st) sr[t] += sr[t+st]; __syncthreads(); }
    float den = sr[0] + 1e-8f;
#pragma unroll
    for (int ii = 0; ii < 8; ++ii) {
        int i = t + ii*256;
        if (i < 45*45) {
            int y = i/45, x = i - y*45;
            float v = vs[ii] + ((y == 22 && x == 22) ? 1e-8f : 0.f);
            kful[y*FH + x] = v / den;
        }
    }
}

// ---------------- Fw0 (direct 9-term DFT of shifted 3x3), image-independent ----------------
__global__ void fw0_kernel(const float* __restrict__ w0c, const float2* __restrict__ Ef,
                           float2* __restrict__ Fw0)
{
    int idx = blockIdx.x*256 + threadIdx.x;
    if (idx >= 48*FH*KF) return;
    int k = idx % KF; int r = idx / KF;
    int c = r & 15; int r2 = r >> 4;
    int ci = r2 % 3; int h = r2 / 3;
    float accx = 0.f, accy = 0.f;
#pragma unroll
    for (int ky = 0; ky < 3; ++ky) {
        int a1 = ky - 1; if (a1 < 0) a1 += FH;
        float2 e1 = Ef[h*FH + a1];
#pragma unroll
        for (int kx = 0; kx < 3; ++kx) {
            int a2 = kx - 1; if (a2 < 0) a2 += FH;
            float2 e2 = Ef[k*FH + a2];
            float wv = w0c[((c*3 + ci)*3 + ky)*3 + kx];
            float tr = e1.x*e2.x - e1.y*e2.y;
            float ti = e1.x*e2.y + e1.y*e2.x;
            accx += wv*tr; accy += wv*ti;
        }
    }
    float2 o; o.x = accx; o.y = accy;
    Fw0[idx] = o;
}

// ---------------- final per-bin 3x3 Hermitian Wiener solve (G images) ----------------
__global__ void wiener_kernel(const float2* __restrict__ Fk, const float2* __restrict__ Fy,
    const float2* __restrict__ Fw0, const float2* __restrict__ Fg2,
    const float* __restrict__ eta, int G, int total, float2* __restrict__ Fx)
{
    int idx = blockIdx.x*256 + threadIdx.x;
    if (idx >= total) return;
    int k = idx % KF; int r = idx / KF;
    int h = r / G;
    float2 fk = Fk[idx];
    float fksq = fk.x*fk.x + fk.y*fk.y;
    float2 fyr = Fy[((size_t)3*r + 0)*KF + k];
    float2 fyg = Fy[((size_t)3*r + 1)*KF + k];
    float2 fyb = Fy[((size_t)3*r + 2)*KF + k];
    float Crr = fksq, Cgg = fksq, Cbb = fksq;
    float2 Crg, Crb, Cgb;
    Crg.x = Crg.y = Crb.x = Crb.y = Cgb.x = Cgb.y = 0.f;
    float2 Br, Bg, Bb;
    Br.x = fk.x*fyr.x + fk.y*fyr.y; Br.y = fk.x*fyr.y - fk.y*fyr.x;
    Bg.x = fk.x*fyg.x + fk.y*fyg.y; Bg.y = fk.x*fyg.y - fk.y*fyg.x;
    Bb.x = fk.x*fyb.x + fk.y*fyb.y; Bb.y = fk.x*fyb.y - fk.y*fyb.x;
    for (int c = 0; c < 16; ++c) {
        float es = 10.f * eta[c];
        float2 wr = Fw0[((size_t)h*48 +  0 + c)*KF + k];
        float2 wg = Fw0[((size_t)h*48 + 16 + c)*KF + k];
        float2 wb = Fw0[((size_t)h*48 + 32 + c)*KF + k];
        float2 g  = Fg2[((size_t)r*16 + c)*KF + k];
        Crr += es*(wr.x*wr.x + wr.y*wr.y);
        Cgg += es*(wg.x*wg.x + wg.y*wg.y);
        Cbb += es*(wb.x*wb.x + wb.y*wb.y);
        Crg.x += es*(wr.x*wg.x + wr.y*wg.y); Crg.y += es*(wr.x*wg.y - wr.y*wg.x);
        Crb.x += es*(wr.x*wb.x + wr.y*wb.y); Crb.y += es*(wr.x*wb.y - wr.y*wb.x);
        Cgb.x += es*(wg.x*wb.x + wg.y*wb.y); Cgb.y += es*(wg.x*wb.y - wg.y*wb.x);
        Br.x += es*(wr.x*g.x + wr.y*g.y); Br.y += es*(wr.x*g.y - wr.y*g.x);
        Bg.x += es*(wg.x*g.x + wg.y*g.y); Bg.y += es*(wg.x*g.y - wg.y*g.x);
        Bb.x += es*(wb.x*g.x + wb.y*g.y); Bb.y += es*(wb.x*g.y - wb.y*g.x);
    }
    float Crg_sq = Crg.x*Crg.x + Crg.y*Crg.y;
    float Crb_sq = Crb.x*Crb.x + Crb.y*Crb.y;
    float Cgb_sq = Cgb.x*Cgb.x + Cgb.y*Cgb.y;
    float Irr = Cgg*Cbb - Cgb_sq;
    float Igg = Crr*Cbb - Crb_sq;
    float Ibb = Crr*Cgg - Crg_sq;
    float2 Irg, Irb, Igb;
    Irg.x = (Cgb.x*Crb.x + Cgb.y*Crb.y) - Cbb*Crg.x;
    Irg.y = (Cgb.x*Crb.y - Cgb.y*Crb.x) - Cbb*Crg.y;
    Irb.x = (Crg.x*Cgb.x - Crg.y*Cgb.y) - Cgg*Crb.x;
    Irb.y = (Crg.x*Cgb.y + Crg.y*Cgb.x) - Cgg*Crb.y;
    Igb.x = (Crg.x*Crb.x + Crg.y*Crb.y) - Crr*Cgb.x;
    Igb.y = (Crg.x*Crb.y - Crg.y*Crb.x) - Crr*Cgb.y;
    float tx_ = Crg.x*Cgb.x - Crg.y*Cgb.y;
    float ty_ = Crg.x*Cgb.y + Crg.y*Cgb.x;
    float den = Crr*Irr - Cgg*Crb_sq - Cbb*Crg_sq + 2.f*(tx_*Crb.x + ty_*Crb.y) + 1e-8f;
    float inv = 1.f/den;
    float2 o;
    o.x = (Irr*Br.x + (Irg.x*Bg.x - Irg.y*Bg.y) + (Irb.x*Bb.x - Irb.y*Bb.y))*inv;
    o.y = (Irr*Br.y + (Irg.x*Bg.y + Irg.y*Bg.x) + (Irb.x*Bb.y + Irb.y*Bb.x))*inv;
    Fx[((size_t)3*r + 0)*KF + k] = o;
    o.x = ((Irg.x*Br.x + Irg.y*Br.y) + Igg*Bg.x + (Igb.x*Bb.x - Igb.y*Bb.y))*inv;
    o.y = ((Irg.x*Br.y - Irg.y*Br.x) + Igg*Bg.y + (Igb.x*Bb.y + Igb.y*Bb.x))*inv;
    Fx[((size_t)3*r + 1)*KF + k] = o;
    o.x = ((Irb.x*Br.x + Irb.y*Br.y) + (Igb.x*Bg.x + Igb.y*Bg.y) + Ibb*Bb.x)*inv;
    o.y = ((Irb.x*Br.y - Irb.y*Br.x) + (Igb.x*Bg.y - Igb.y*Bg.x) + Ibb*Bb.y)*inv;
    Fx[((size_t)3*r + 2)*KF + k] = o;
}

// ---------------- output assembly (G images) ----------------
__global__ void crop_kernel(const float* __restrict__ sp, float* __restrict__ outp, int total)
{
    int idx = blockIdx.x*256 + threadIdx.x;
    if (idx >= total) return;
    int x = idx & 255; int r = idx >> 8; int y = r & 255; int plane = r >> 8;
    outp[idx] = sp[((size_t)plane*FH + (y+22))*FH + (x+22)];
}

__global__ void kcopy_kernel(const float* __restrict__ kful, float* __restrict__ outp, int total)
{
    int idx = blockIdx.x*256 + threadIdx.x;
    if (idx >= total) return;
    int rem = idx % 2025; int img = idx / 2025;
    int x = rem % 45; int y = rem / 45;
    outp[idx] = kful[(size_t)img*FH*FH + y*FH + x];
}

// =====================================================================
extern "C" void kernel_launch(void* const* d_in, const int* in_sizes, int n_in,
                              void* d_out, int out_size, void* d_ws, size_t ws_size,
                              hipStream_t stream)
{
    (void)in_sizes; (void)n_in; (void)out_size;
    const float* blurred = (const float*)d_in[0];
    const float* w0      = (const float*)d_in[1];
    const float* wsw     = (const float*)d_in[2];
    const float* biases  = (const float*)d_in[3];
    const float* kbias   = (const float*)d_in[4];
    const float* kprox   = (const float*)d_in[5];
    const float* zetas   = (const float*)d_in[6];
    const float* eta     = (const float*)d_in[7];
    float* outp = (float*)d_out;

    auto al = [](size_t b) { return (b + 255) & ~(size_t)255; };
    auto need = [&](int G) -> size_t {
        size_t s = 0;
        s += al((size_t)FH*FH*8);                 // Ef
        s += 4*al((size_t)KP*KP*2);               // EfH, EfL, EiH, EiL
        s += 2*al((size_t)448*FH*2);              // TtH, TtL
        s += 2*al((size_t)FH*416*2);              // UtH, UtL
        s += al(432*4);                           // w0c
        s += al((size_t)10*G*16*65536*4);         // fyN
        s += al((size_t)G*16*FH*FH*4);            // zsp
        s += 3*al((size_t)G*16*FH*KF*8);          // mid, FzFg, Ffy
        s += 3*al((size_t)G*FH*KF*8);             // Fk, kfA, kfB
        s += 2*al((size_t)G*FH*FH*4);             // kraw, kful
        s += 2*al((size_t)G*3*FH*KF*8);           // FyB, FxB
        s += al((size_t)G*64*8) + al(256);        // lseP, kmax
        return s;
    };
    int G = 4;
    while (G > 1 && need(G) > ws_size) G >>= 1;

    char* base = (char*)d_ws;
    size_t off = 0;
    auto alloc = [&](size_t bytes) -> void* {
        void* p = (void*)(base + off);
        off += (bytes + 255) & ~(size_t)255;
        return p;
    };
    float2* Ef   = (float2*)alloc((size_t)FH*FH*8);
    unsigned short* EfH = (unsigned short*)alloc((size_t)KP*KP*2);
    unsigned short* EfL = (unsigned short*)alloc((size_t)KP*KP*2);
    unsigned short* EiH = (unsigned short*)alloc((size_t)KP*KP*2);
    unsigned short* EiL = (unsigned short*)alloc((size_t)KP*KP*2);
    unsigned short* TtH = (unsigned short*)alloc((size_t)448*FH*2);
    unsigned short* TtL = (unsigned short*)alloc((size_t)448*FH*2);
    unsigned short* UtH = (unsigned short*)alloc((size_t)FH*416*2);
    unsigned short* UtL = (unsigned short*)alloc((size_t)FH*416*2);
    float*  w0cB = (float*)alloc(432*4);
    float*  fyN  = (float*)alloc((size_t)10*G*16*65536*4);
    float*  zsp  = (float*)alloc((size_t)G*16*FH*FH*4);
    float2* mid  = (float2*)alloc((size_t)G*16*FH*KF*8);
    float2* FzFg = (float2*)alloc((size_t)G*16*FH*KF*8);
    float2* Ffy  = (float2*)alloc((size_t)G*16*FH*KF*8);
    float2* Fk   = (float2*)alloc((size_t)G*FH*KF*8);
    float2* kfA  = (float2*)alloc((size_t)G*FH*KF*8);
    float2* kfB  = (float2*)alloc((size_t)G*FH*KF*8);
    float*  kraw = (float*)alloc((size_t)G*FH*FH*4);
    float*  kful = (float*)alloc((size_t)G*FH*FH*4);
    float2* FyB  = (float2*)alloc((size_t)G*3*FH*KF*8);
    float2* FxB  = (float2*)alloc((size_t)G*3*FH*KF*8);
    float2* lseP = (float2*)alloc((size_t)G*64*8);
    float*  kmaxB= (float*)alloc(256);
    // Fw0 (28.45 MB) overlays fyN (>= 41.9 MB even at G=1) — dead by final stage
    float2* Fw0B = (float2*)fyN;

    // tables + weight prep (image-independent)
    init_ef_k<<<(FH*FH+255)/256, 256, 0, stream>>>(Ef);
    init_estack<<<(KP*KP+255)/256, 256, 0, stream>>>(EfH, EfL, 0);
    init_estack<<<(KP*KP+255)/256, 256, 0, stream>>>(EiH, EiL, 1);
    init_tt<<<(448*FH+255)/256, 256, 0, stream>>>(TtH, TtL);
    init_ut<<<(FH*416+255)/256, 256, 0, stream>>>(UtH, UtL);
    w0c_kernel<<<1, 64, 0, stream>>>(w0, w0cB);

    auto zg = [&](const unsigned short* EH, const unsigned short* EL,
                  const float2* Bm, float2* Cm, int Ncols) {
        zgemm_col_mfma<<<dim3((Ncols+63)/64, (2*FH)/128), 256, 0, stream>>>(
            EH, EL, Bm, (float*)Cm, Ncols);
    };
    auto r2c = [&](const float* inp, int inH, int inW, int oY, int oX,
                   const float* thr, float2* o, int B) {
        r2c_row_mfma<<<dim3(7, 3, B), 256, 0, stream>>>(
            inp, inH, inW, oY, oX, thr, TtH, TtL, (float*)o, B);
    };
    auto c2r = [&](const float2* Ain, float* o, int B) {
        c2r_row_mfma<<<dim3(6, 3, B), 256, 0, stream>>>(
            (const float*)Ain, UtH, UtL, o, B);
    };

    const size_t IMG16 = (size_t)16*65536;
    const size_t LAY   = (size_t)G*IMG16;

    for (int g0 = 0; g0 < 4; g0 += G) {
        const float* img = blurred + (size_t)g0*3*65536;

        // forward conv chain
        conv3x3_kernel<<<dim3(16,16,G), 256, 0, stream>>>(
            img, w0cB, fyN, 3, 1, (size_t)3*65536, IMG16);
        for (int l = 1; l < 10; ++l)
            conv3x3_kernel<<<dim3(16,16,G), 256, 0, stream>>>(
                fyN + (size_t)(l-1)*LAY, wsw + (size_t)(l-1)*2304,
                fyN + (size_t)l*LAY, 16, 0, IMG16, IMG16);

        // z init (circshift + threshold b0), Fz
        int totZ = G*16*FH*FH;
        zinit_kernel<<<(totZ+255)/256, 256, 0, stream>>>(fyN + 9*LAY, biases, zsp, totZ);
        r2c(zsp, FH, FH, 0, 0, nullptr, mid, G*16);
        zg(EfH, EfL, mid, FzFg, G*16*KF);

        // k init = delta
        zero_kernel<<<(G*FH*FH+255)/256, 256, 0, stream>>>(kful, G*FH*FH);
        kdelta_kernel<<<1, 64, 0, stream>>>(kful, G);

        int totS = G*16*FH*KF;
        int totK = G*FH*KF;
        for (int it = 0; it < 10; ++it) {
            int Lfy = 9 - it;
            r2c(fyN + (size_t)Lfy*LAY, 256, 256, 44, 44, nullptr, mid, G*16);
            zg(EfH, EfL, mid, Ffy, G*16*KF);
            r2c(kful, FH, FH, 0, 0, nullptr, mid, G);
            zg(EfH, EfL, mid, Fk, G*KF);
            fg_kernel<<<(totS+255)/256, 256, 0, stream>>>(Ffy, FzFg, Fk, zetas, it, totS, FzFg);
            zg(EiH, EiL, FzFg, mid, G*16*KF);
            c2r(mid, zsp, G*16);                    // zsp = irfft(Fg) PRE-threshold
            r2c(zsp, FH, FH, 0, 0, biases + (it+1)*16, mid, G*16);  // fused soft-threshold
            zg(EfH, EfL, mid, FzFg, G*16*KF);       // Fz_new
            knum_kernel<<<(totK+255)/256, 256, 0, stream>>>(FzFg, Ffy, Fk, kprox, it, totK, kfA);
            zg(EiH, EiL, kfA, kfB, G*KF);
            c2r(kfB, kraw, G);
            lse_part_kernel<<<dim3(64,G), 256, 0, stream>>>(kraw, lseP);
            lse_final_kernel<<<G, 64, 0, stream>>>(lseP, kmaxB);
            knew_kernel<<<G, 256, 0, stream>>>(kraw, kmaxB, kbias, it, kful);
        }

        // ---- final stage for this group ----
        r2c(img, 256, 256, 44, 44, nullptr, mid, 3*G);
        zg(EfH, EfL, mid, FyB, 3*G*KF);
        r2c(kful, FH, FH, 0, 0, nullptr, mid, G);
        zg(EfH, EfL, mid, Fk, G*KF);
        // Fg2 = rfft(softt(zsp, b_final))
        r2c(zsp, FH, FH, 0, 0, biases + 11*16, mid, G*16);
        zg(EfH, EfL, mid, FzFg, G*16*KF);
        fw0_kernel<<<(48*FH*KF+255)/256, 256, 0, stream>>>(w0cB, Ef, Fw0B);
        wiener_kernel<<<(totK+255)/256, 256, 0, stream>>>(Fk, FyB, Fw0B, FzFg, eta, G, totK, FxB);
        zg(EiH, EiL, FxB, mid, 3*G*KF);
        c2r(mid, zsp, 3*G);
        int totC = G*3*65536;
        crop_kernel<<<(totC+255)/256, 256, 0, stream>>>(zsp, outp + (size_t)g0*3*65536, totC);
        int totKC = G*2025;
        kcopy_kernel<<<(totKC+255)/256, 256, 0, stream>>>(kful, outp + 786432 + g0*2025, totKC);
    }
}